// Round 1
// 1081.233 us; speedup vs baseline: 1.1290x; 1.1290x over previous
//
#include <hip/hip_runtime.h>
#include <float.h>
#include <math.h>

// ---------------------------------------------------------------------------
// MABlock: q/k/v/w projections -> attn over batch keys -> FAISS-style exact
// top-8 retrieval from FIFO memory -> attn over retrieved keys -> Wo + gate.
//
// Round 3: search_kernel rewritten on MFMA. The Q.K_new similarity scan
// (previously fp32 VALU, 447us, MfmaUtil=0) now uses the same split-bf16
// 3-product 16x16x32 MFMA as attn_kernel's QK^T (~5e-5 abs error on sims vs
// ~0.14 8th/9th order-stat gap -> top-8 set is stable). Per-lane top-8 lists
// + width-16 shuffle merge reproduce exact top_k tie-break semantics.
// Norm-bound check + exact old-memory fallback preserved (also MFMA).
// ---------------------------------------------------------------------------

#define DIN   1024
#define NHEADS 16
#define HD    64
#define NB    4
#define NSEQ  512
#define BN    2048          // NB*NSEQ
#define MEMN  32768
#define OLDN  30720         // MEMN - BN
#define IPQ   8
#define ATT_SCALE 0.125f
#define SZ    (BN * DIN)    // 2097152 floats

typedef __attribute__((ext_vector_type(4))) float floatx4;
typedef __attribute__((ext_vector_type(8))) short short8;

__device__ __forceinline__ unsigned short f2bf(float f) {
    unsigned int u = __float_as_uint(f);
    return (unsigned short)((u + 0x7FFFu + ((u >> 16) & 1u)) >> 16);
}
__device__ __forceinline__ float bf2f(unsigned short s) {
    return __uint_as_float(((unsigned int)s) << 16);
}
__device__ __forceinline__ void split_pack(float4 a, float4 b, short8 &hi, short8 &lo) {
    float vals[8] = {a.x, a.y, a.z, a.w, b.x, b.y, b.z, b.w};
#pragma unroll
    for (int j = 0; j < 8; ++j) {
        unsigned short h = f2bf(vals[j]);
        hi[j] = (short)h;
        lo[j] = (short)f2bf(vals[j] - bf2f(h));
    }
}
__device__ __forceinline__ floatx4 mfma16(short8 a, short8 b, floatx4 c) {
    return __builtin_amdgcn_mfma_f32_16x16x32_bf16(a, b, c, 0, 0, 0);
}

// ---------------------------------------------------------------------------
// init: zero the 16 per-head max-old-norm slots (ws is poisoned 0xAA)
// ---------------------------------------------------------------------------
__global__ void init_kernel(unsigned int* nrm) {
    if (threadIdx.x < NHEADS) nrm[threadIdx.x] = 0u;
}

// ---------------------------------------------------------------------------
// MFMA GEMM: C[z][M][1024] = A[M][1024] @ W[z][1024][1024]^T (NT, k-major).
// 128x128 block tile, 4 waves in 2x2 of 64x64 wave tiles, K-step 32.
// Staging converts fp32 -> split bf16 (hi,lo) into LDS; 4-product mfma.
// C/D layout per 16x16 subtile: row = quad*4+reg, col = l16.
// sigmoidZ: z index that gets a sigmoid epilogue (-1 = none).
// ---------------------------------------------------------------------------
__global__ __launch_bounds__(256) void gemm_mfma(
    const float* __restrict__ A,
    const float* __restrict__ W0, const float* __restrict__ W1,
    const float* __restrict__ W2, const float* __restrict__ W3,
    float* __restrict__ C0, float* __restrict__ C1,
    float* __restrict__ C2, float* __restrict__ C3,
    int sigmoidZ)
{
    __shared__ short Ahi_s[128 * 32];
    __shared__ short Alo_s[128 * 32];
    __shared__ short Bhi_s[128 * 32];
    __shared__ short Blo_s[128 * 32];

    int z = blockIdx.z;
    const float* W = (z == 0) ? W0 : (z == 1) ? W1 : (z == 2) ? W2 : W3;
    float* C = (z == 0) ? C0 : (z == 1) ? C1 : (z == 2) ? C2 : C3;

    int tid = threadIdx.x;
    int wv = tid >> 6, lane = tid & 63, quad = lane >> 4, l16 = lane & 15;
    int row0 = blockIdx.y * 128, col0 = blockIdx.x * 128;
    int wm = (wv >> 1) * 64, wn = (wv & 1) * 64;

    floatx4 zero4 = {0.f, 0.f, 0.f, 0.f};
    floatx4 acc[4][4];
#pragma unroll
    for (int i = 0; i < 4; ++i)
#pragma unroll
        for (int j = 0; j < 4; ++j) acc[i][j] = zero4;

    for (int kk = 0; kk < DIN; kk += 32) {
        __syncthreads();
        // stage 128x32 of A and W, split fp32 -> bf16 hi/lo
#pragma unroll
        for (int p = 0; p < 2; ++p) {
            int g = tid * 2 + p;              // 8-float group, 0..511
            int row = g >> 2, cc = (g & 3) * 8;
            const float* ap = A + (size_t)(row0 + row) * DIN + kk + cc;
            float4 a0 = *(const float4*)ap;
            float4 a1 = *(const float4*)(ap + 4);
            short8 h8, l8;
            split_pack(a0, a1, h8, l8);
            *(short8*)&Ahi_s[g * 8] = h8;
            *(short8*)&Alo_s[g * 8] = l8;
            const float* bp = W + (size_t)(col0 + row) * DIN + kk + cc;
            float4 b0 = *(const float4*)bp;
            float4 b1 = *(const float4*)(bp + 4);
            split_pack(b0, b1, h8, l8);
            *(short8*)&Bhi_s[g * 8] = h8;
            *(short8*)&Blo_s[g * 8] = l8;
        }
        __syncthreads();

        short8 ah[4], al[4], bh[4], bl[4];
#pragma unroll
        for (int t = 0; t < 4; ++t) {
            int ar = (wm + t * 16 + l16) * 32 + quad * 8;
            int br = (wn + t * 16 + l16) * 32 + quad * 8;
            ah[t] = *(const short8*)&Ahi_s[ar];
            al[t] = *(const short8*)&Alo_s[ar];
            bh[t] = *(const short8*)&Bhi_s[br];
            bl[t] = *(const short8*)&Blo_s[br];
        }
#pragma unroll
        for (int tm = 0; tm < 4; ++tm)
#pragma unroll
            for (int tn = 0; tn < 4; ++tn) {
                floatx4 c = acc[tm][tn];
                c = mfma16(al[tm], bl[tn], c);
                c = mfma16(al[tm], bh[tn], c);
                c = mfma16(ah[tm], bl[tn], c);
                c = mfma16(ah[tm], bh[tn], c);
                acc[tm][tn] = c;
            }
    }

    bool sig = (sigmoidZ == z);
#pragma unroll
    for (int tm = 0; tm < 4; ++tm)
#pragma unroll
        for (int tn = 0; tn < 4; ++tn)
#pragma unroll
            for (int r = 0; r < 4; ++r) {
                int row = row0 + wm + tm * 16 + quad * 4 + r;
                int col = col0 + wn + tn * 16 + l16;
                float vv = acc[tm][tn][r];
                if (sig) vv = 1.f / (1.f + __expf(-vv));
                C[(size_t)row * DIN + col] = vv;
            }
}

// ---------------------------------------------------------------------------
// per-head max L2 norm over the 30720 surviving old memory keys
// grid (30, 16), 256 threads; 16 lanes per row.
// ---------------------------------------------------------------------------
__global__ __launch_bounds__(256) void oldnorm_kernel(
    const float* __restrict__ kmem0, unsigned int* __restrict__ nrm)
{
    int h = blockIdx.y;
    int c0 = blockIdx.x * 1024;
    int part = threadIdx.x & 15, rg = threadIdx.x >> 4;
    const float* base = kmem0 + ((size_t)h * MEMN + BN) * HD;
    float mx = 0.f;
    for (int it = 0; it < 64; ++it) {
        int row = c0 + it * 16 + rg;
        float4 vv = *(const float4*)(base + (size_t)row * HD + part * 4);
        float s = vv.x * vv.x + vv.y * vv.y + vv.z * vv.z + vv.w * vv.w;
#pragma unroll
        for (int o = 1; o < 16; o <<= 1) s += __shfl_xor(s, o, 16);
        mx = fmaxf(mx, s);
    }
    __shared__ float red[256];
    red[threadIdx.x] = mx;
    __syncthreads();
    for (int st = 128; st > 0; st >>= 1) {
        if (threadIdx.x < st) red[threadIdx.x] = fmaxf(red[threadIdx.x], red[threadIdx.x + st]);
        __syncthreads();
    }
    if (threadIdx.x == 0) atomicMax(nrm + h, __float_as_uint(sqrtf(red[0])));
}

// ---------------------------------------------------------------------------
// search (MFMA): per (h, 64-query block) exact top-8 over the 2048 new keys.
// 4 waves x 16 queries. Per 32-key chunk: stage K hi/lo bf16 in LDS (same
// layout as attn_kernel), S = QK^T via 3-product split-bf16 mfma, then each
// lane inserts its 8 S-values (4 query rows x 2 key cols) into per-row top-8
// lists. Merge across the 16 lanes of a quad (val desc, idx asc = top_k).
// Bound check |q|*maxOldNorm >= val8 -> exact MFMA scan of old memory.
// ---------------------------------------------------------------------------
__device__ __forceinline__ void insert_top8(float (&tv)[8], int (&ti)[8], float v, int id) {
    if (v < tv[7] || (v == tv[7] && id > ti[7])) return;
    tv[7] = v; ti[7] = id;
#pragma unroll
    for (int s = 7; s > 0; --s) {
        bool sw = (tv[s] > tv[s - 1]) || (tv[s] == tv[s - 1] && ti[s] < ti[s - 1]);
        if (sw) {
            float fv = tv[s]; tv[s] = tv[s - 1]; tv[s - 1] = fv;
            int iv = ti[s]; ti[s] = ti[s - 1]; ti[s - 1] = iv;
        }
    }
}

__global__ __launch_bounds__(256, 2) void search_kernel(
    const float* __restrict__ q, const float* __restrict__ knew,
    const float* __restrict__ kmem0, const unsigned int* __restrict__ nrm,
    int* __restrict__ idxOut)
{
    __shared__ short Khi[32 * 72];
    __shared__ short Klo[32 * 72];
    __shared__ int sflag;
    int tid = threadIdx.x;
    int qt = blockIdx.x, h = blockIdx.y;
    int wv = tid >> 6, lane = tid & 63, quad = lane >> 4, l16 = lane & 15;
    if (tid == 0) sflag = 0;

    // persistent Q fragments (A-operand: row=l16, k=quad*8+j, step st*32)
    short8 qhi[2], qlo[2];
    float qn2;   // |q_row(l16)|^2, replicated across quads after reduce
    {
        int qrow = qt * 64 + wv * 16 + l16;
        const float* qp = q + (size_t)qrow * DIN + h * HD;
        float sq = 0.f;
#pragma unroll
        for (int st = 0; st < 2; ++st) {
            float4 a = *(const float4*)(qp + st * 32 + quad * 8);
            float4 c = *(const float4*)(qp + st * 32 + quad * 8 + 4);
            sq += a.x * a.x + a.y * a.y + a.z * a.z + a.w * a.w
                + c.x * c.x + c.y * c.y + c.z * c.z + c.w * c.w;
            split_pack(a, c, qhi[st], qlo[st]);
        }
        sq += __shfl_xor(sq, 16);   // reduce over quad bit0
        sq += __shfl_xor(sq, 32);   // reduce over quad bit1
        qn2 = sq;
    }

    float tv[4][8]; int ti[4][8];
#pragma unroll
    for (int r = 0; r < 4; ++r)
#pragma unroll
        for (int s = 0; s < 8; ++s) { tv[r][s] = -FLT_MAX; ti[r][s] = 0x7FFFFFFF; }

    // ---- phase A: 2048 new keys, 64 chunks of 32 ----
    for (int ch = 0; ch < 64; ++ch) {
        __syncthreads();
        {   // stage 32 K rows, split fp32 -> bf16 hi/lo
            int key = tid >> 3, part = tid & 7;
            const float* kr = knew + (size_t)(ch * 32 + key) * DIN + h * HD;
            float4 ka = *(const float4*)(kr + part * 8);
            float4 kb = *(const float4*)(kr + part * 8 + 4);
            short8 kh8, kl8;
            split_pack(ka, kb, kh8, kl8);
            *(short8*)&Khi[key * 72 + part * 8] = kh8;
            *(short8*)&Klo[key * 72 + part * 8] = kl8;
        }
        __syncthreads();

        short8 kh00 = *(const short8*)&Khi[l16 * 72 + quad * 8];
        short8 kh01 = *(const short8*)&Khi[l16 * 72 + 32 + quad * 8];
        short8 kl00 = *(const short8*)&Klo[l16 * 72 + quad * 8];
        short8 kl01 = *(const short8*)&Klo[l16 * 72 + 32 + quad * 8];
        short8 kh10 = *(const short8*)&Khi[(16 + l16) * 72 + quad * 8];
        short8 kh11 = *(const short8*)&Khi[(16 + l16) * 72 + 32 + quad * 8];
        short8 kl10 = *(const short8*)&Klo[(16 + l16) * 72 + quad * 8];
        short8 kl11 = *(const short8*)&Klo[(16 + l16) * 72 + 32 + quad * 8];
        floatx4 zero4 = {0.f, 0.f, 0.f, 0.f};
        floatx4 s0 = zero4, s1 = zero4;
        s0 = mfma16(qhi[0], kh00, s0); s0 = mfma16(qhi[1], kh01, s0);
        s0 = mfma16(qlo[0], kh00, s0); s0 = mfma16(qlo[1], kh01, s0);
        s0 = mfma16(qhi[0], kl00, s0); s0 = mfma16(qhi[1], kl01, s0);
        s1 = mfma16(qhi[0], kh10, s1); s1 = mfma16(qhi[1], kh11, s1);
        s1 = mfma16(qlo[0], kh10, s1); s1 = mfma16(qlo[1], kh11, s1);
        s1 = mfma16(qhi[0], kl10, s1); s1 = mfma16(qhi[1], kl11, s1);

        int base = OLDN + ch * 32;
#pragma unroll
        for (int r = 0; r < 4; ++r) {
            insert_top8(tv[r], ti[r], s0[r], base + l16);
            insert_top8(tv[r], ti[r], s1[r], base + 16 + l16);
        }
    }

    // ---- merge #1 across the 16 lanes of each quad ----
    float val8[4], keepv[4];
    int keepi[4];
#pragma unroll
    for (int rr = 0; rr < 4; ++rr) { keepv[rr] = -FLT_MAX; keepi[rr] = 0x7FFFFFFF; val8[rr] = -FLT_MAX; }
#pragma unroll
    for (int rr = 0; rr < 4; ++rr) {
#pragma unroll
        for (int m = 0; m < 8; ++m) {
            float cv = tv[rr][0]; int ci = ti[rr][0];
#pragma unroll
            for (int o = 1; o < 16; o <<= 1) {
                float ov = __shfl_xor(cv, o, 16);
                int oi = __shfl_xor(ci, o, 16);
                if (ov > cv || (ov == cv && oi < ci)) { cv = ov; ci = oi; }
            }
            if (tv[rr][0] == cv && ti[rr][0] == ci) {
#pragma unroll
                for (int s = 0; s < 7; ++s) { tv[rr][s] = tv[rr][s + 1]; ti[rr][s] = ti[rr][s + 1]; }
                tv[rr][7] = -FLT_MAX; ti[rr][7] = 0x7FFFFFFF;
            }
            if (l16 == m) { keepv[rr] = cv; keepi[rr] = ci; }
            if (l16 == 0)
                idxOut[((size_t)h * BN + qt * 64 + wv * 16 + quad * 4 + rr) * IPQ + m] = ci;
            val8[rr] = cv;
        }
    }

    // ---- bound check: can any old key enter the top-8? ----
    float oldMax = __uint_as_float(nrm[h]);
    bool need = false;
#pragma unroll
    for (int rr = 0; rr < 4; ++rr) {
        float bq = __shfl(qn2, quad * 4 + rr, 16);
        float bnd = sqrtf(bq) * oldMax * 1.0001f + 1e-5f;
        if (bnd >= val8[rr]) need = true;
    }
    if (need) sflag = 1;
    __syncthreads();

    if (sflag) {
        // rebuild per-lane lists: lanes l16<8 hold winner m=l16, rest empty
#pragma unroll
        for (int rr = 0; rr < 4; ++rr) {
            tv[rr][0] = (l16 < 8) ? keepv[rr] : -FLT_MAX;
            ti[rr][0] = (l16 < 8) ? keepi[rr] : 0x7FFFFFFF;
#pragma unroll
            for (int s = 1; s < 8; ++s) { tv[rr][s] = -FLT_MAX; ti[rr][s] = 0x7FFFFFFF; }
        }
        // exact scan of the 30720 surviving old keys, 960 chunks of 32
        for (int ch = 0; ch < 960; ++ch) {
            __syncthreads();
            {
                int key = tid >> 3, part = tid & 7;
                const float* kr = kmem0 + ((size_t)h * MEMN + BN + ch * 32 + key) * HD;
                float4 ka = *(const float4*)(kr + part * 8);
                float4 kb = *(const float4*)(kr + part * 8 + 4);
                short8 kh8, kl8;
                split_pack(ka, kb, kh8, kl8);
                *(short8*)&Khi[key * 72 + part * 8] = kh8;
                *(short8*)&Klo[key * 72 + part * 8] = kl8;
            }
            __syncthreads();

            short8 kh00 = *(const short8*)&Khi[l16 * 72 + quad * 8];
            short8 kh01 = *(const short8*)&Khi[l16 * 72 + 32 + quad * 8];
            short8 kl00 = *(const short8*)&Klo[l16 * 72 + quad * 8];
            short8 kl01 = *(const short8*)&Klo[l16 * 72 + 32 + quad * 8];
            short8 kh10 = *(const short8*)&Khi[(16 + l16) * 72 + quad * 8];
            short8 kh11 = *(const short8*)&Khi[(16 + l16) * 72 + 32 + quad * 8];
            short8 kl10 = *(const short8*)&Klo[(16 + l16) * 72 + quad * 8];
            short8 kl11 = *(const short8*)&Klo[(16 + l16) * 72 + 32 + quad * 8];
            floatx4 zero4 = {0.f, 0.f, 0.f, 0.f};
            floatx4 s0 = zero4, s1 = zero4;
            s0 = mfma16(qhi[0], kh00, s0); s0 = mfma16(qhi[1], kh01, s0);
            s0 = mfma16(qlo[0], kh00, s0); s0 = mfma16(qlo[1], kh01, s0);
            s0 = mfma16(qhi[0], kl00, s0); s0 = mfma16(qhi[1], kl01, s0);
            s1 = mfma16(qhi[0], kh10, s1); s1 = mfma16(qhi[1], kh11, s1);
            s1 = mfma16(qlo[0], kh10, s1); s1 = mfma16(qlo[1], kh11, s1);
            s1 = mfma16(qhi[0], kl10, s1); s1 = mfma16(qhi[1], kl11, s1);

            int base = ch * 32;
#pragma unroll
            for (int r = 0; r < 4; ++r) {
                insert_top8(tv[r], ti[r], s0[r], base + l16);
                insert_top8(tv[r], ti[r], s1[r], base + 16 + l16);
            }
        }
        // merge #2 (final)
#pragma unroll
        for (int rr = 0; rr < 4; ++rr) {
#pragma unroll
            for (int m = 0; m < 8; ++m) {
                float cv = tv[rr][0]; int ci = ti[rr][0];
#pragma unroll
                for (int o = 1; o < 16; o <<= 1) {
                    float ov = __shfl_xor(cv, o, 16);
                    int oi = __shfl_xor(ci, o, 16);
                    if (ov > cv || (ov == cv && oi < ci)) { cv = ov; ci = oi; }
                }
                if (tv[rr][0] == cv && ti[rr][0] == ci) {
#pragma unroll
                    for (int s = 0; s < 7; ++s) { tv[rr][s] = tv[rr][s + 1]; ti[rr][s] = ti[rr][s + 1]; }
                    tv[rr][7] = -FLT_MAX; ti[rr][7] = 0x7FFFFFFF;
                }
                if (l16 == 0)
                    idxOut[((size_t)h * BN + qt * 64 + wv * 16 + quad * 4 + rr) * IPQ + m] = ci;
            }
        }
    }
}

// ---------------------------------------------------------------------------
// MFMA flash attention. Block = 4 waves x 16 queries = 64 queries per (b,h).
// Per 32-key chunk: stage K (hi/lo bf16, row-major) and V^T (hi/lo, dim-major)
// in LDS; S = QK^T via 3-product split-bf16 mfma; online softmax per wave
// (quad-row layout, width-16 shuffles); P round-trips LDS to A-frag layout;
// O += P*Vhi + P*Vlo.  gatherMode=1 resolves rows through idx (memory attn).
// ---------------------------------------------------------------------------
__global__ __launch_bounds__(256, 2) void attn_kernel(
    const float* __restrict__ q, const float* __restrict__ knew,
    const float* __restrict__ vnew, const float* __restrict__ kmem0,
    const float* __restrict__ vmem0, const int* __restrict__ idxb,
    float* __restrict__ outp, int gatherMode, int nkeys)
{
    __shared__ short Khi[32 * 72];
    __shared__ short Klo[32 * 72];
    __shared__ short Vthi[64 * 40];
    __shared__ short Vtlo[64 * 40];
    __shared__ short Pbuf[4 * 16 * 40];
    int tid = threadIdx.x;
    int qt = blockIdx.x, h = blockIdx.y, b = blockIdx.z;
    int wv = tid >> 6, lane = tid & 63, quad = lane >> 4, l16 = lane & 15;

    // persistent Q fragments (A-operand layout: row=l16, k=quad*8+j, step*32)
    short8 qhi[2], qlo[2];
    {
        int qrow = b * NSEQ + qt * 64 + wv * 16 + l16;
        const float* qp = q + (size_t)qrow * DIN + h * HD;
#pragma unroll
        for (int st = 0; st < 2; ++st) {
            float4 a = *(const float4*)(qp + st * 32 + quad * 8);
            float4 c = *(const float4*)(qp + st * 32 + quad * 8 + 4);
            split_pack(a, c, qhi[st], qlo[st]);
        }
    }
    floatx4 zero4 = {0.f, 0.f, 0.f, 0.f};
    floatx4 Oacc[4];
#pragma unroll
    for (int t = 0; t < 4; ++t) Oacc[t] = zero4;
    float mrow[4], lrow[4];
#pragma unroll
    for (int r = 0; r < 4; ++r) { mrow[r] = -3.0e38f; lrow[r] = 0.f; }

    int nch = nkeys >> 5;
    for (int ch = 0; ch < nch; ++ch) {
        __syncthreads();
        { // stage 32 K rows + 32 V rows (transposed), split to bf16 hi/lo
            int key = tid >> 3, part = tid & 7;
            const float *kr, *vr;
            if (!gatherMode) {
                int row = b * NSEQ + ch * 32 + key;
                kr = knew + (size_t)row * DIN + h * HD;
                vr = vnew + (size_t)row * DIN + h * HD;
            } else {
                int J = ch * 32 + key;
                int mi = idxb[((size_t)h * BN + b * NSEQ + (J >> 3)) * IPQ + (J & 7)];
                if (mi < OLDN) {
                    kr = kmem0 + ((size_t)h * MEMN + BN + mi) * HD;
                    vr = vmem0 + ((size_t)h * MEMN + BN + mi) * HD;
                } else {
                    kr = knew + (size_t)(mi - OLDN) * DIN + h * HD;
                    vr = vnew + (size_t)(mi - OLDN) * DIN + h * HD;
                }
            }
            float4 ka = *(const float4*)(kr + part * 8);
            float4 kb = *(const float4*)(kr + part * 8 + 4);
            short8 kh8, kl8;
            split_pack(ka, kb, kh8, kl8);
            *(short8*)&Khi[key * 72 + part * 8] = kh8;
            *(short8*)&Klo[key * 72 + part * 8] = kl8;
            float4 va = *(const float4*)(vr + part * 8);
            float4 vb = *(const float4*)(vr + part * 8 + 4);
            float vals[8] = {va.x, va.y, va.z, va.w, vb.x, vb.y, vb.z, vb.w};
#pragma unroll
            for (int u = 0; u < 8; ++u) {
                int d = part * 8 + u;
                unsigned short hh = f2bf(vals[u]);
                Vthi[d * 40 + key] = (short)hh;
                Vtlo[d * 40 + key] = (short)f2bf(vals[u] - bf2f(hh));
            }
        }
        __syncthreads();

        // S = Q K^T (two 16-key col tiles), split-bf16 3-product
        short8 kh00 = *(const short8*)&Khi[(l16) * 72 + 0 * 32 + quad * 8];
        short8 kh01 = *(const short8*)&Khi[(l16) * 72 + 1 * 32 + quad * 8];
        short8 kl00 = *(const short8*)&Klo[(l16) * 72 + 0 * 32 + quad * 8];
        short8 kl01 = *(const short8*)&Klo[(l16) * 72 + 1 * 32 + quad * 8];
        short8 kh10 = *(const short8*)&Khi[(16 + l16) * 72 + 0 * 32 + quad * 8];
        short8 kh11 = *(const short8*)&Khi[(16 + l16) * 72 + 1 * 32 + quad * 8];
        short8 kl10 = *(const short8*)&Klo[(16 + l16) * 72 + 0 * 32 + quad * 8];
        short8 kl11 = *(const short8*)&Klo[(16 + l16) * 72 + 1 * 32 + quad * 8];
        floatx4 s0 = zero4, s1 = zero4;
        s0 = mfma16(qhi[0], kh00, s0); s0 = mfma16(qhi[1], kh01, s0);
        s0 = mfma16(qlo[0], kh00, s0); s0 = mfma16(qlo[1], kh01, s0);
        s0 = mfma16(qhi[0], kl00, s0); s0 = mfma16(qhi[1], kl01, s0);
        s1 = mfma16(qhi[0], kh10, s1); s1 = mfma16(qhi[1], kh11, s1);
        s1 = mfma16(qlo[0], kh10, s1); s1 = mfma16(qlo[1], kh11, s1);
        s1 = mfma16(qhi[0], kl10, s1); s1 = mfma16(qhi[1], kl11, s1);

        // online softmax (rows = quad*4+r, cols spread over 16 lanes)
        float cm[4], alpha[4], p0[4], p1[4], rs[4];
#pragma unroll
        for (int r = 0; r < 4; ++r) cm[r] = fmaxf(s0[r], s1[r]) * ATT_SCALE;
#pragma unroll
        for (int o = 1; o < 16; o <<= 1) {
#pragma unroll
            for (int r = 0; r < 4; ++r) cm[r] = fmaxf(cm[r], __shfl_xor(cm[r], o, 16));
        }
#pragma unroll
        for (int r = 0; r < 4; ++r) {
            float mn = fmaxf(mrow[r], cm[r]);
            alpha[r] = __expf(mrow[r] - mn);
            p0[r] = __expf(s0[r] * ATT_SCALE - mn);
            p1[r] = __expf(s1[r] * ATT_SCALE - mn);
            mrow[r] = mn;
            rs[r] = p0[r] + p1[r];
        }
#pragma unroll
        for (int o = 1; o < 16; o <<= 1) {
#pragma unroll
            for (int r = 0; r < 4; ++r) rs[r] += __shfl_xor(rs[r], o, 16);
        }
#pragma unroll
        for (int r = 0; r < 4; ++r) {
            lrow[r] = lrow[r] * alpha[r] + rs[r];
            Pbuf[(wv * 16 + quad * 4 + r) * 40 + l16] = (short)f2bf(p0[r]);
            Pbuf[(wv * 16 + quad * 4 + r) * 40 + 16 + l16] = (short)f2bf(p1[r]);
        }
#pragma unroll
        for (int t = 0; t < 4; ++t)
#pragma unroll
            for (int r = 0; r < 4; ++r) Oacc[t][r] *= alpha[r];
        __syncthreads();   // P (and Vt) visible to frag reads

        short8 pf = *(const short8*)&Pbuf[(wv * 16 + l16) * 40 + quad * 8];
#pragma unroll
        for (int t = 0; t < 4; ++t) {
            short8 vh = *(const short8*)&Vthi[(t * 16 + l16) * 40 + quad * 8];
            short8 vl = *(const short8*)&Vtlo[(t * 16 + l16) * 40 + quad * 8];
            floatx4 o = Oacc[t];
            o = mfma16(pf, vh, o);
            o = mfma16(pf, vl, o);
            Oacc[t] = o;
        }
    }
    // epilogue: divide by l, write (D rows = quad*4+r, cols = t*16+l16)
#pragma unroll
    for (int t = 0; t < 4; ++t)
#pragma unroll
        for (int r = 0; r < 4; ++r) {
            int qrow = b * NSEQ + qt * 64 + wv * 16 + quad * 4 + r;
            outp[(size_t)qrow * DIN + h * HD + t * 16 + l16] = Oacc[t][r] / lrow[r];
        }
}

// ---------------------------------------------------------------------------
// out = w*G1 + (1-w)*G2 + bo   (bias factors out of the gate)
// ---------------------------------------------------------------------------
__global__ __launch_bounds__(256) void combine_kernel(
    const float* __restrict__ G, const float* __restrict__ wg,
    const float* __restrict__ bo, float* __restrict__ out)
{
    int gid = blockIdx.x * 256 + threadIdx.x;     // f4 index, 524288 total
    float4 g1 = ((const float4*)G)[gid];
    float4 g2 = ((const float4*)G)[gid + (SZ / 4)];
    float4 w4 = ((const float4*)wg)[gid];
    float4 b4 = ((const float4*)bo)[gid & (DIN / 4 - 1)];
    float4 o;
    o.x = w4.x * g1.x + (1.f - w4.x) * g2.x + b4.x;
    o.y = w4.y * g1.y + (1.f - w4.y) * g2.y + b4.y;
    o.z = w4.z * g1.z + (1.f - w4.z) * g2.z + b4.z;
    o.w = w4.w * g1.w + (1.f - w4.w) * g2.w + b4.w;
    ((float4*)out)[gid] = o;
}

// ---------------------------------------------------------------------------
extern "C" void kernel_launch(void* const* d_in, const int* in_sizes, int n_in,
                              void* d_out, int out_size, void* d_ws, size_t ws_size,
                              hipStream_t stream)
{
    (void)in_sizes; (void)n_in; (void)out_size; (void)ws_size;
    const float* x     = (const float*)d_in[0];
    const float* Wq    = (const float*)d_in[1];
    const float* Wk    = (const float*)d_in[2];
    const float* Wv    = (const float*)d_in[3];
    const float* Ww    = (const float*)d_in[4];
    const float* Wo    = (const float*)d_in[5];
    const float* bo    = (const float*)d_in[6];
    const float* kmem0 = (const float*)d_in[7];
    const float* vmem0 = (const float*)d_in[8];

    float* ws = (float*)d_ws;
    float* q  = ws;
    float* k  = ws + (size_t)SZ;
    float* v  = ws + (size_t)2 * SZ;
    float* wg = ws + (size_t)3 * SZ;
    float* AO = ws + (size_t)4 * SZ;          // 2*SZ (rows 0..2047 = a, 2048.. = a_m)
    float* G  = ws + (size_t)6 * SZ;          // 2*SZ
    int* idxb = (int*)(ws + (size_t)8 * SZ);  // 16*2048*8
    unsigned int* nrm = (unsigned int*)(ws + (size_t)8 * SZ + NHEADS * BN * IPQ);

    init_kernel<<<1, 64, 0, stream>>>(nrm);
    gemm_mfma<<<dim3(8, 16, 4), 256, 0, stream>>>(x, Wq, Wk, Wv, Ww, q, k, v, wg, 3);
    oldnorm_kernel<<<dim3(30, 16), 256, 0, stream>>>(kmem0, nrm);
    search_kernel<<<dim3(32, 16), 256, 0, stream>>>(q, k, kmem0, nrm, idxb);
    attn_kernel<<<dim3(8, 16, 4), 256, 0, stream>>>(q, k, v, kmem0, vmem0, idxb, AO, 0, 512);
    attn_kernel<<<dim3(8, 16, 4), 256, 0, stream>>>(q, k, v, kmem0, vmem0, idxb,
                                                    AO + (size_t)SZ, 1, 4096);
    gemm_mfma<<<dim3(8, 32, 1), 256, 0, stream>>>(AO, Wo, Wo, Wo, Wo, G, G, G, G, -1);
    combine_kernel<<<2048, 256, 0, stream>>>(G, wg, bo, (float*)d_out);
}

// Round 2
// 998.347 us; speedup vs baseline: 1.2227x; 1.0830x over previous
//
#include <hip/hip_runtime.h>
#include <float.h>
#include <math.h>

// ---------------------------------------------------------------------------
// MABlock: q/k/v/w projections -> attn over batch keys -> FAISS-style exact
// top-8 retrieval from FIFO memory -> attn over retrieved keys -> Wo + gate.
//
// Round 4: attn_kernel de-bottlenecked.
//  - V^T staging writes XOR-swizzled (16-way bank conflict -> ~4-way).
//  - Pbuf barrier removed (per-wave round-trip; lgkmcnt ordering suffices).
//  - Chunk gather loads register-prefetched; barriers are raw s_barrier with
//    lgkmcnt(0) only, so global loads stay in flight across chunk boundaries.
//  - Grid remapped to (pair, qt) so the 8 qt-blocks of one (h,b) share an XCD.
// ---------------------------------------------------------------------------

#define DIN   1024
#define NHEADS 16
#define HD    64
#define NB    4
#define NSEQ  512
#define BN    2048          // NB*NSEQ
#define MEMN  32768
#define OLDN  30720         // MEMN - BN
#define IPQ   8
#define ATT_SCALE 0.125f
#define SZ    (BN * DIN)    // 2097152 floats

typedef __attribute__((ext_vector_type(4))) float floatx4;
typedef __attribute__((ext_vector_type(8))) short short8;

__device__ __forceinline__ unsigned short f2bf(float f) {
    unsigned int u = __float_as_uint(f);
    return (unsigned short)((u + 0x7FFFu + ((u >> 16) & 1u)) >> 16);
}
__device__ __forceinline__ float bf2f(unsigned short s) {
    return __uint_as_float(((unsigned int)s) << 16);
}
__device__ __forceinline__ void split_pack(float4 a, float4 b, short8 &hi, short8 &lo) {
    float vals[8] = {a.x, a.y, a.z, a.w, b.x, b.y, b.z, b.w};
#pragma unroll
    for (int j = 0; j < 8; ++j) {
        unsigned short h = f2bf(vals[j]);
        hi[j] = (short)h;
        lo[j] = (short)f2bf(vals[j] - bf2f(h));
    }
}
__device__ __forceinline__ floatx4 mfma16(short8 a, short8 b, floatx4 c) {
    return __builtin_amdgcn_mfma_f32_16x16x32_bf16(a, b, c, 0, 0, 0);
}

// ---------------------------------------------------------------------------
// init: zero the 16 per-head max-old-norm slots (ws is poisoned 0xAA)
// ---------------------------------------------------------------------------
__global__ void init_kernel(unsigned int* nrm) {
    if (threadIdx.x < NHEADS) nrm[threadIdx.x] = 0u;
}

// ---------------------------------------------------------------------------
// MFMA GEMM: C[z][M][1024] = A[M][1024] @ W[z][1024][1024]^T (NT, k-major).
// 128x128 block tile, 4 waves in 2x2 of 64x64 wave tiles, K-step 32.
// Staging converts fp32 -> split bf16 (hi,lo) into LDS; 4-product mfma.
// C/D layout per 16x16 subtile: row = quad*4+reg, col = l16.
// sigmoidZ: z index that gets a sigmoid epilogue (-1 = none).
// ---------------------------------------------------------------------------
__global__ __launch_bounds__(256) void gemm_mfma(
    const float* __restrict__ A,
    const float* __restrict__ W0, const float* __restrict__ W1,
    const float* __restrict__ W2, const float* __restrict__ W3,
    float* __restrict__ C0, float* __restrict__ C1,
    float* __restrict__ C2, float* __restrict__ C3,
    int sigmoidZ)
{
    __shared__ short Ahi_s[128 * 32];
    __shared__ short Alo_s[128 * 32];
    __shared__ short Bhi_s[128 * 32];
    __shared__ short Blo_s[128 * 32];

    int z = blockIdx.z;
    const float* W = (z == 0) ? W0 : (z == 1) ? W1 : (z == 2) ? W2 : W3;
    float* C = (z == 0) ? C0 : (z == 1) ? C1 : (z == 2) ? C2 : C3;

    int tid = threadIdx.x;
    int wv = tid >> 6, lane = tid & 63, quad = lane >> 4, l16 = lane & 15;
    int row0 = blockIdx.y * 128, col0 = blockIdx.x * 128;
    int wm = (wv >> 1) * 64, wn = (wv & 1) * 64;

    floatx4 zero4 = {0.f, 0.f, 0.f, 0.f};
    floatx4 acc[4][4];
#pragma unroll
    for (int i = 0; i < 4; ++i)
#pragma unroll
        for (int j = 0; j < 4; ++j) acc[i][j] = zero4;

    for (int kk = 0; kk < DIN; kk += 32) {
        __syncthreads();
        // stage 128x32 of A and W, split fp32 -> bf16 hi/lo
#pragma unroll
        for (int p = 0; p < 2; ++p) {
            int g = tid * 2 + p;              // 8-float group, 0..511
            int row = g >> 2, cc = (g & 3) * 8;
            const float* ap = A + (size_t)(row0 + row) * DIN + kk + cc;
            float4 a0 = *(const float4*)ap;
            float4 a1 = *(const float4*)(ap + 4);
            short8 h8, l8;
            split_pack(a0, a1, h8, l8);
            *(short8*)&Ahi_s[g * 8] = h8;
            *(short8*)&Alo_s[g * 8] = l8;
            const float* bp = W + (size_t)(col0 + row) * DIN + kk + cc;
            float4 b0 = *(const float4*)bp;
            float4 b1 = *(const float4*)(bp + 4);
            split_pack(b0, b1, h8, l8);
            *(short8*)&Bhi_s[g * 8] = h8;
            *(short8*)&Blo_s[g * 8] = l8;
        }
        __syncthreads();

        short8 ah[4], al[4], bh[4], bl[4];
#pragma unroll
        for (int t = 0; t < 4; ++t) {
            int ar = (wm + t * 16 + l16) * 32 + quad * 8;
            int br = (wn + t * 16 + l16) * 32 + quad * 8;
            ah[t] = *(const short8*)&Ahi_s[ar];
            al[t] = *(const short8*)&Alo_s[ar];
            bh[t] = *(const short8*)&Bhi_s[br];
            bl[t] = *(const short8*)&Blo_s[br];
        }
#pragma unroll
        for (int tm = 0; tm < 4; ++tm)
#pragma unroll
            for (int tn = 0; tn < 4; ++tn) {
                floatx4 c = acc[tm][tn];
                c = mfma16(al[tm], bl[tn], c);
                c = mfma16(al[tm], bh[tn], c);
                c = mfma16(ah[tm], bl[tn], c);
                c = mfma16(ah[tm], bh[tn], c);
                acc[tm][tn] = c;
            }
    }

    bool sig = (sigmoidZ == z);
#pragma unroll
    for (int tm = 0; tm < 4; ++tm)
#pragma unroll
        for (int tn = 0; tn < 4; ++tn)
#pragma unroll
            for (int r = 0; r < 4; ++r) {
                int row = row0 + wm + tm * 16 + quad * 4 + r;
                int col = col0 + wn + tn * 16 + l16;
                float vv = acc[tm][tn][r];
                if (sig) vv = 1.f / (1.f + __expf(-vv));
                C[(size_t)row * DIN + col] = vv;
            }
}

// ---------------------------------------------------------------------------
// per-head max L2 norm over the 30720 surviving old memory keys
// grid (30, 16), 256 threads; 16 lanes per row.
// ---------------------------------------------------------------------------
__global__ __launch_bounds__(256) void oldnorm_kernel(
    const float* __restrict__ kmem0, unsigned int* __restrict__ nrm)
{
    int h = blockIdx.y;
    int c0 = blockIdx.x * 1024;
    int part = threadIdx.x & 15, rg = threadIdx.x >> 4;
    const float* base = kmem0 + ((size_t)h * MEMN + BN) * HD;
    float mx = 0.f;
    for (int it = 0; it < 64; ++it) {
        int row = c0 + it * 16 + rg;
        float4 vv = *(const float4*)(base + (size_t)row * HD + part * 4);
        float s = vv.x * vv.x + vv.y * vv.y + vv.z * vv.z + vv.w * vv.w;
#pragma unroll
        for (int o = 1; o < 16; o <<= 1) s += __shfl_xor(s, o, 16);
        mx = fmaxf(mx, s);
    }
    __shared__ float red[256];
    red[threadIdx.x] = mx;
    __syncthreads();
    for (int st = 128; st > 0; st >>= 1) {
        if (threadIdx.x < st) red[threadIdx.x] = fmaxf(red[threadIdx.x], red[threadIdx.x + st]);
        __syncthreads();
    }
    if (threadIdx.x == 0) atomicMax(nrm + h, __float_as_uint(sqrtf(red[0])));
}

// ---------------------------------------------------------------------------
// search (MFMA): per (h, 64-query block) exact top-8 over the 2048 new keys.
// 4 waves x 16 queries. Per 32-key chunk: stage K hi/lo bf16 in LDS (same
// layout as attn_kernel), S = QK^T via 3-product split-bf16 mfma, then each
// lane inserts its 8 S-values (4 query rows x 2 key cols) into per-row top-8
// lists. Merge across the 16 lanes of a quad (val desc, idx asc = top_k).
// Bound check |q|*maxOldNorm >= val8 -> exact MFMA scan of old memory.
// ---------------------------------------------------------------------------
__device__ __forceinline__ void insert_top8(float (&tv)[8], int (&ti)[8], float v, int id) {
    if (v < tv[7] || (v == tv[7] && id > ti[7])) return;
    tv[7] = v; ti[7] = id;
#pragma unroll
    for (int s = 7; s > 0; --s) {
        bool sw = (tv[s] > tv[s - 1]) || (tv[s] == tv[s - 1] && ti[s] < ti[s - 1]);
        if (sw) {
            float fv = tv[s]; tv[s] = tv[s - 1]; tv[s - 1] = fv;
            int iv = ti[s]; ti[s] = ti[s - 1]; ti[s - 1] = iv;
        }
    }
}

__global__ __launch_bounds__(256, 2) void search_kernel(
    const float* __restrict__ q, const float* __restrict__ knew,
    const float* __restrict__ kmem0, const unsigned int* __restrict__ nrm,
    int* __restrict__ idxOut)
{
    __shared__ short Khi[32 * 72];
    __shared__ short Klo[32 * 72];
    __shared__ int sflag;
    int tid = threadIdx.x;
    int qt = blockIdx.x, h = blockIdx.y;
    int wv = tid >> 6, lane = tid & 63, quad = lane >> 4, l16 = lane & 15;
    if (tid == 0) sflag = 0;

    // persistent Q fragments (A-operand: row=l16, k=quad*8+j, step st*32)
    short8 qhi[2], qlo[2];
    float qn2;   // |q_row(l16)|^2, replicated across quads after reduce
    {
        int qrow = qt * 64 + wv * 16 + l16;
        const float* qp = q + (size_t)qrow * DIN + h * HD;
        float sq = 0.f;
#pragma unroll
        for (int st = 0; st < 2; ++st) {
            float4 a = *(const float4*)(qp + st * 32 + quad * 8);
            float4 c = *(const float4*)(qp + st * 32 + quad * 8 + 4);
            sq += a.x * a.x + a.y * a.y + a.z * a.z + a.w * a.w
                + c.x * c.x + c.y * c.y + c.z * c.z + c.w * c.w;
            split_pack(a, c, qhi[st], qlo[st]);
        }
        sq += __shfl_xor(sq, 16);   // reduce over quad bit0
        sq += __shfl_xor(sq, 32);   // reduce over quad bit1
        qn2 = sq;
    }

    float tv[4][8]; int ti[4][8];
#pragma unroll
    for (int r = 0; r < 4; ++r)
#pragma unroll
        for (int s = 0; s < 8; ++s) { tv[r][s] = -FLT_MAX; ti[r][s] = 0x7FFFFFFF; }

    // ---- phase A: 2048 new keys, 64 chunks of 32 ----
    for (int ch = 0; ch < 64; ++ch) {
        __syncthreads();
        {   // stage 32 K rows, split fp32 -> bf16 hi/lo
            int key = tid >> 3, part = tid & 7;
            const float* kr = knew + (size_t)(ch * 32 + key) * DIN + h * HD;
            float4 ka = *(const float4*)(kr + part * 8);
            float4 kb = *(const float4*)(kr + part * 8 + 4);
            short8 kh8, kl8;
            split_pack(ka, kb, kh8, kl8);
            *(short8*)&Khi[key * 72 + part * 8] = kh8;
            *(short8*)&Klo[key * 72 + part * 8] = kl8;
        }
        __syncthreads();

        short8 kh00 = *(const short8*)&Khi[l16 * 72 + quad * 8];
        short8 kh01 = *(const short8*)&Khi[l16 * 72 + 32 + quad * 8];
        short8 kl00 = *(const short8*)&Klo[l16 * 72 + quad * 8];
        short8 kl01 = *(const short8*)&Klo[l16 * 72 + 32 + quad * 8];
        short8 kh10 = *(const short8*)&Khi[(16 + l16) * 72 + quad * 8];
        short8 kh11 = *(const short8*)&Khi[(16 + l16) * 72 + 32 + quad * 8];
        short8 kl10 = *(const short8*)&Klo[(16 + l16) * 72 + quad * 8];
        short8 kl11 = *(const short8*)&Klo[(16 + l16) * 72 + 32 + quad * 8];
        floatx4 zero4 = {0.f, 0.f, 0.f, 0.f};
        floatx4 s0 = zero4, s1 = zero4;
        s0 = mfma16(qhi[0], kh00, s0); s0 = mfma16(qhi[1], kh01, s0);
        s0 = mfma16(qlo[0], kh00, s0); s0 = mfma16(qlo[1], kh01, s0);
        s0 = mfma16(qhi[0], kl00, s0); s0 = mfma16(qhi[1], kl01, s0);
        s1 = mfma16(qhi[0], kh10, s1); s1 = mfma16(qhi[1], kh11, s1);
        s1 = mfma16(qlo[0], kh10, s1); s1 = mfma16(qlo[1], kh11, s1);
        s1 = mfma16(qhi[0], kl10, s1); s1 = mfma16(qhi[1], kl11, s1);

        int base = OLDN + ch * 32;
#pragma unroll
        for (int r = 0; r < 4; ++r) {
            insert_top8(tv[r], ti[r], s0[r], base + l16);
            insert_top8(tv[r], ti[r], s1[r], base + 16 + l16);
        }
    }

    // ---- merge #1 across the 16 lanes of each quad ----
    float val8[4], keepv[4];
    int keepi[4];
#pragma unroll
    for (int rr = 0; rr < 4; ++rr) { keepv[rr] = -FLT_MAX; keepi[rr] = 0x7FFFFFFF; val8[rr] = -FLT_MAX; }
#pragma unroll
    for (int rr = 0; rr < 4; ++rr) {
#pragma unroll
        for (int m = 0; m < 8; ++m) {
            float cv = tv[rr][0]; int ci = ti[rr][0];
#pragma unroll
            for (int o = 1; o < 16; o <<= 1) {
                float ov = __shfl_xor(cv, o, 16);
                int oi = __shfl_xor(ci, o, 16);
                if (ov > cv || (ov == cv && oi < ci)) { cv = ov; ci = oi; }
            }
            if (tv[rr][0] == cv && ti[rr][0] == ci) {
#pragma unroll
                for (int s = 0; s < 7; ++s) { tv[rr][s] = tv[rr][s + 1]; ti[rr][s] = ti[rr][s + 1]; }
                tv[rr][7] = -FLT_MAX; ti[rr][7] = 0x7FFFFFFF;
            }
            if (l16 == m) { keepv[rr] = cv; keepi[rr] = ci; }
            if (l16 == 0)
                idxOut[((size_t)h * BN + qt * 64 + wv * 16 + quad * 4 + rr) * IPQ + m] = ci;
            val8[rr] = cv;
        }
    }

    // ---- bound check: can any old key enter the top-8? ----
    float oldMax = __uint_as_float(nrm[h]);
    bool need = false;
#pragma unroll
    for (int rr = 0; rr < 4; ++rr) {
        float bq = __shfl(qn2, quad * 4 + rr, 16);
        float bnd = sqrtf(bq) * oldMax * 1.0001f + 1e-5f;
        if (bnd >= val8[rr]) need = true;
    }
    if (need) sflag = 1;
    __syncthreads();

    if (sflag) {
        // rebuild per-lane lists: lanes l16<8 hold winner m=l16, rest empty
#pragma unroll
        for (int rr = 0; rr < 4; ++rr) {
            tv[rr][0] = (l16 < 8) ? keepv[rr] : -FLT_MAX;
            ti[rr][0] = (l16 < 8) ? keepi[rr] : 0x7FFFFFFF;
#pragma unroll
            for (int s = 1; s < 8; ++s) { tv[rr][s] = -FLT_MAX; ti[rr][s] = 0x7FFFFFFF; }
        }
        // exact scan of the 30720 surviving old keys, 960 chunks of 32
        for (int ch = 0; ch < 960; ++ch) {
            __syncthreads();
            {
                int key = tid >> 3, part = tid & 7;
                const float* kr = kmem0 + ((size_t)h * MEMN + BN + ch * 32 + key) * HD;
                float4 ka = *(const float4*)(kr + part * 8);
                float4 kb = *(const float4*)(kr + part * 8 + 4);
                short8 kh8, kl8;
                split_pack(ka, kb, kh8, kl8);
                *(short8*)&Khi[key * 72 + part * 8] = kh8;
                *(short8*)&Klo[key * 72 + part * 8] = kl8;
            }
            __syncthreads();

            short8 kh00 = *(const short8*)&Khi[l16 * 72 + quad * 8];
            short8 kh01 = *(const short8*)&Khi[l16 * 72 + 32 + quad * 8];
            short8 kl00 = *(const short8*)&Klo[l16 * 72 + quad * 8];
            short8 kl01 = *(const short8*)&Klo[l16 * 72 + 32 + quad * 8];
            short8 kh10 = *(const short8*)&Khi[(16 + l16) * 72 + quad * 8];
            short8 kh11 = *(const short8*)&Khi[(16 + l16) * 72 + 32 + quad * 8];
            short8 kl10 = *(const short8*)&Klo[(16 + l16) * 72 + quad * 8];
            short8 kl11 = *(const short8*)&Klo[(16 + l16) * 72 + 32 + quad * 8];
            floatx4 zero4 = {0.f, 0.f, 0.f, 0.f};
            floatx4 s0 = zero4, s1 = zero4;
            s0 = mfma16(qhi[0], kh00, s0); s0 = mfma16(qhi[1], kh01, s0);
            s0 = mfma16(qlo[0], kh00, s0); s0 = mfma16(qlo[1], kh01, s0);
            s0 = mfma16(qhi[0], kl00, s0); s0 = mfma16(qhi[1], kl01, s0);
            s1 = mfma16(qhi[0], kh10, s1); s1 = mfma16(qhi[1], kh11, s1);
            s1 = mfma16(qlo[0], kh10, s1); s1 = mfma16(qlo[1], kh11, s1);
            s1 = mfma16(qhi[0], kl10, s1); s1 = mfma16(qhi[1], kl11, s1);

            int base = ch * 32;
#pragma unroll
            for (int r = 0; r < 4; ++r) {
                insert_top8(tv[r], ti[r], s0[r], base + l16);
                insert_top8(tv[r], ti[r], s1[r], base + 16 + l16);
            }
        }
        // merge #2 (final)
#pragma unroll
        for (int rr = 0; rr < 4; ++rr) {
#pragma unroll
            for (int m = 0; m < 8; ++m) {
                float cv = tv[rr][0]; int ci = ti[rr][0];
#pragma unroll
                for (int o = 1; o < 16; o <<= 1) {
                    float ov = __shfl_xor(cv, o, 16);
                    int oi = __shfl_xor(ci, o, 16);
                    if (ov > cv || (ov == cv && oi < ci)) { cv = ov; ci = oi; }
                }
                if (tv[rr][0] == cv && ti[rr][0] == ci) {
#pragma unroll
                    for (int s = 0; s < 7; ++s) { tv[rr][s] = tv[rr][s + 1]; ti[rr][s] = ti[rr][s + 1]; }
                    tv[rr][7] = -FLT_MAX; ti[rr][7] = 0x7FFFFFFF;
                }
                if (l16 == 0)
                    idxOut[((size_t)h * BN + qt * 64 + wv * 16 + quad * 4 + rr) * IPQ + m] = ci;
            }
        }
    }
}

// ---------------------------------------------------------------------------
// MFMA flash attention. Grid (pair=h*4+b, qt): the 8 qt-blocks of one (h,b)
// share an XCD (flat%8 = pair%8) for gather L2 reuse. Block = 4 waves x 16
// queries. Per 32-key chunk: gather loads are register-prefetched one chunk
// ahead; staging converts fp32 -> split-bf16 into LDS (V^T writes
// XOR-swizzled on the key axis to break the 16-way bank conflict); barriers
// are raw s_barrier + lgkmcnt(0) so prefetched global loads stay in flight.
// S = QK^T (3-product split-bf16), per-wave online softmax, P via per-wave
// LDS round-trip (no barrier needed), O += P*Vhi + P*Vlo.
// ---------------------------------------------------------------------------
__global__ __launch_bounds__(256, 2) void attn_kernel(
    const float* __restrict__ q, const float* __restrict__ knew,
    const float* __restrict__ vnew, const float* __restrict__ kmem0,
    const float* __restrict__ vmem0, const int* __restrict__ idxb,
    float* __restrict__ outp, int gatherMode, int nkeys)
{
    __shared__ short Khi[32 * 72];
    __shared__ short Klo[32 * 72];
    __shared__ short Vthi[64 * 40];
    __shared__ short Vtlo[64 * 40];
    __shared__ short Pbuf[4 * 16 * 40];
    int tid = threadIdx.x;
    int pair = blockIdx.x, qt = blockIdx.y;
    int h = pair >> 2, b = pair & 3;
    int wv = tid >> 6, lane = tid & 63, quad = lane >> 4, l16 = lane & 15;

    // persistent Q fragments (A-operand layout: row=l16, k=quad*8+j, step*32)
    short8 qhi[2], qlo[2];
    {
        int qrow = b * NSEQ + qt * 64 + wv * 16 + l16;
        const float* qp = q + (size_t)qrow * DIN + h * HD;
#pragma unroll
        for (int st = 0; st < 2; ++st) {
            float4 a = *(const float4*)(qp + st * 32 + quad * 8);
            float4 c = *(const float4*)(qp + st * 32 + quad * 8 + 4);
            split_pack(a, c, qhi[st], qlo[st]);
        }
    }
    floatx4 zero4 = {0.f, 0.f, 0.f, 0.f};
    floatx4 Oacc[4];
#pragma unroll
    for (int t = 0; t < 4; ++t) Oacc[t] = zero4;
    float mrow[4], lrow[4];
#pragma unroll
    for (int r = 0; r < 4; ++r) { mrow[r] = -3.0e38f; lrow[r] = 0.f; }

    int key = tid >> 3, part = tid & 7;
    // V^T swizzled column for this thread's key (d>>3 == part for all 8 d's)
    int vcol = (((key >> 3) ^ (part & 3)) << 3) | (key & 7);
    float4 ka, kb, va, vb;                // prefetched gather registers
    auto gload = [&](int chl) {
        const float *kr, *vr;
        if (!gatherMode) {
            int row = b * NSEQ + chl * 32 + key;
            kr = knew + (size_t)row * DIN + h * HD;
            vr = vnew + (size_t)row * DIN + h * HD;
        } else {
            int J = chl * 32 + key;
            int mi = idxb[((size_t)h * BN + b * NSEQ + (J >> 3)) * IPQ + (J & 7)];
            if (mi < OLDN) {
                kr = kmem0 + ((size_t)h * MEMN + BN + mi) * HD;
                vr = vmem0 + ((size_t)h * MEMN + BN + mi) * HD;
            } else {
                kr = knew + (size_t)(mi - OLDN) * DIN + h * HD;
                vr = vnew + (size_t)(mi - OLDN) * DIN + h * HD;
            }
        }
        ka = *(const float4*)(kr + part * 8);
        kb = *(const float4*)(kr + part * 8 + 4);
        va = *(const float4*)(vr + part * 8);
        vb = *(const float4*)(vr + part * 8 + 4);
    };

    int nch = nkeys >> 5;
    gload(0);                             // prologue prefetch
    for (int ch = 0; ch < nch; ++ch) {
        // barrier #1: previous chunk's LDS reads done before overwrite.
        // LDS-only dependency -> lgkmcnt is sufficient; vmcnt (prefetched
        // gather loads) intentionally stays in flight.
        asm volatile("s_waitcnt lgkmcnt(0)" ::: "memory");
        __builtin_amdgcn_s_barrier();

        { // stage prefetched K row + V row (transposed, swizzled) as bf16 hi/lo
            short8 kh8, kl8;
            split_pack(ka, kb, kh8, kl8);
            *(short8*)&Khi[key * 72 + part * 8] = kh8;
            *(short8*)&Klo[key * 72 + part * 8] = kl8;
            float vals[8] = {va.x, va.y, va.z, va.w, vb.x, vb.y, vb.z, vb.w};
#pragma unroll
            for (int u = 0; u < 8; ++u) {
                int d = part * 8 + u;
                unsigned short hh = f2bf(vals[u]);
                Vthi[d * 40 + vcol] = (short)hh;
                Vtlo[d * 40 + vcol] = (short)f2bf(vals[u] - bf2f(hh));
            }
        }
        if (ch + 1 < nch) gload(ch + 1); // issue next gather; hides under MFMA

        // barrier #2: staging visible to all waves (again lgkmcnt only)
        asm volatile("s_waitcnt lgkmcnt(0)" ::: "memory");
        __builtin_amdgcn_s_barrier();

        // S = Q K^T (two 16-key col tiles), split-bf16 3-product
        short8 kh00 = *(const short8*)&Khi[(l16) * 72 + 0 * 32 + quad * 8];
        short8 kh01 = *(const short8*)&Khi[(l16) * 72 + 1 * 32 + quad * 8];
        short8 kl00 = *(const short8*)&Klo[(l16) * 72 + 0 * 32 + quad * 8];
        short8 kl01 = *(const short8*)&Klo[(l16) * 72 + 1 * 32 + quad * 8];
        short8 kh10 = *(const short8*)&Khi[(16 + l16) * 72 + 0 * 32 + quad * 8];
        short8 kh11 = *(const short8*)&Khi[(16 + l16) * 72 + 1 * 32 + quad * 8];
        short8 kl10 = *(const short8*)&Klo[(16 + l16) * 72 + 0 * 32 + quad * 8];
        short8 kl11 = *(const short8*)&Klo[(16 + l16) * 72 + 1 * 32 + quad * 8];
        floatx4 s0 = zero4, s1 = zero4;
        s0 = mfma16(qhi[0], kh00, s0); s0 = mfma16(qhi[1], kh01, s0);
        s0 = mfma16(qlo[0], kh00, s0); s0 = mfma16(qlo[1], kh01, s0);
        s0 = mfma16(qhi[0], kl00, s0); s0 = mfma16(qhi[1], kl01, s0);
        s1 = mfma16(qhi[0], kh10, s1); s1 = mfma16(qhi[1], kh11, s1);
        s1 = mfma16(qlo[0], kh10, s1); s1 = mfma16(qlo[1], kh11, s1);
        s1 = mfma16(qhi[0], kl10, s1); s1 = mfma16(qhi[1], kl11, s1);

        // online softmax (rows = quad*4+r, cols spread over 16 lanes)
        float cm[4], alpha[4], p0[4], p1[4], rs[4];
#pragma unroll
        for (int r = 0; r < 4; ++r) cm[r] = fmaxf(s0[r], s1[r]) * ATT_SCALE;
#pragma unroll
        for (int o = 1; o < 16; o <<= 1) {
#pragma unroll
            for (int r = 0; r < 4; ++r) cm[r] = fmaxf(cm[r], __shfl_xor(cm[r], o, 16));
        }
#pragma unroll
        for (int r = 0; r < 4; ++r) {
            float mn = fmaxf(mrow[r], cm[r]);
            alpha[r] = __expf(mrow[r] - mn);
            p0[r] = __expf(s0[r] * ATT_SCALE - mn);
            p1[r] = __expf(s1[r] * ATT_SCALE - mn);
            mrow[r] = mn;
            rs[r] = p0[r] + p1[r];
        }
#pragma unroll
        for (int o = 1; o < 16; o <<= 1) {
#pragma unroll
            for (int r = 0; r < 4; ++r) rs[r] += __shfl_xor(rs[r], o, 16);
        }
#pragma unroll
        for (int r = 0; r < 4; ++r) {
            lrow[r] = lrow[r] * alpha[r] + rs[r];
            Pbuf[(wv * 16 + quad * 4 + r) * 40 + l16] = (short)f2bf(p0[r]);
            Pbuf[(wv * 16 + quad * 4 + r) * 40 + 16 + l16] = (short)f2bf(p1[r]);
        }
#pragma unroll
        for (int t = 0; t < 4; ++t)
#pragma unroll
            for (int r = 0; r < 4; ++r) Oacc[t][r] *= alpha[r];
        // Pbuf round-trip is per-wave (both sides indexed by wv): no barrier.
        // Vt reads are protected by barrier #2; compiler orders Pbuf
        // write->read via lgkmcnt (may-alias LDS).

        short8 pf = *(const short8*)&Pbuf[(wv * 16 + l16) * 40 + quad * 8];
#pragma unroll
        for (int t = 0; t < 4; ++t) {
            int dd = t * 16 + l16;
            int vc = ((quad ^ ((dd >> 3) & 3)) << 3);
            short8 vh = *(const short8*)&Vthi[dd * 40 + vc];
            short8 vl = *(const short8*)&Vtlo[dd * 40 + vc];
            floatx4 o = Oacc[t];
            o = mfma16(pf, vh, o);
            o = mfma16(pf, vl, o);
            Oacc[t] = o;
        }
    }
    // epilogue: divide by l, write (D rows = quad*4+r, cols = t*16+l16)
#pragma unroll
    for (int t = 0; t < 4; ++t)
#pragma unroll
        for (int r = 0; r < 4; ++r) {
            int qrow = b * NSEQ + qt * 64 + wv * 16 + quad * 4 + r;
            outp[(size_t)qrow * DIN + h * HD + t * 16 + l16] = Oacc[t][r] / lrow[r];
        }
}

// ---------------------------------------------------------------------------
// out = w*G1 + (1-w)*G2 + bo   (bias factors out of the gate)
// ---------------------------------------------------------------------------
__global__ __launch_bounds__(256) void combine_kernel(
    const float* __restrict__ G, const float* __restrict__ wg,
    const float* __restrict__ bo, float* __restrict__ out)
{
    int gid = blockIdx.x * 256 + threadIdx.x;     // f4 index, 524288 total
    float4 g1 = ((const float4*)G)[gid];
    float4 g2 = ((const float4*)G)[gid + (SZ / 4)];
    float4 w4 = ((const float4*)wg)[gid];
    float4 b4 = ((const float4*)bo)[gid & (DIN / 4 - 1)];
    float4 o;
    o.x = w4.x * g1.x + (1.f - w4.x) * g2.x + b4.x;
    o.y = w4.y * g1.y + (1.f - w4.y) * g2.y + b4.y;
    o.z = w4.z * g1.z + (1.f - w4.z) * g2.z + b4.z;
    o.w = w4.w * g1.w + (1.f - w4.w) * g2.w + b4.w;
    ((float4*)out)[gid] = o;
}

// ---------------------------------------------------------------------------
extern "C" void kernel_launch(void* const* d_in, const int* in_sizes, int n_in,
                              void* d_out, int out_size, void* d_ws, size_t ws_size,
                              hipStream_t stream)
{
    (void)in_sizes; (void)n_in; (void)out_size; (void)ws_size;
    const float* x     = (const float*)d_in[0];
    const float* Wq    = (const float*)d_in[1];
    const float* Wk    = (const float*)d_in[2];
    const float* Wv    = (const float*)d_in[3];
    const float* Ww    = (const float*)d_in[4];
    const float* Wo    = (const float*)d_in[5];
    const float* bo    = (const float*)d_in[6];
    const float* kmem0 = (const float*)d_in[7];
    const float* vmem0 = (const float*)d_in[8];

    float* ws = (float*)d_ws;
    float* q  = ws;
    float* k  = ws + (size_t)SZ;
    float* v  = ws + (size_t)2 * SZ;
    float* wg = ws + (size_t)3 * SZ;
    float* AO = ws + (size_t)4 * SZ;          // 2*SZ (rows 0..2047 = a, 2048.. = a_m)
    float* G  = ws + (size_t)6 * SZ;          // 2*SZ
    int* idxb = (int*)(ws + (size_t)8 * SZ);  // 16*2048*8
    unsigned int* nrm = (unsigned int*)(ws + (size_t)8 * SZ + NHEADS * BN * IPQ);

    init_kernel<<<1, 64, 0, stream>>>(nrm);
    gemm_mfma<<<dim3(8, 16, 4), 256, 0, stream>>>(x, Wq, Wk, Wv, Ww, q, k, v, wg, 3);
    oldnorm_kernel<<<dim3(30, 16), 256, 0, stream>>>(kmem0, nrm);
    search_kernel<<<dim3(32, 16), 256, 0, stream>>>(q, k, kmem0, nrm, idxb);
    attn_kernel<<<dim3(64, 8, 1), 256, 0, stream>>>(q, k, v, kmem0, vmem0, idxb, AO, 0, 512);
    attn_kernel<<<dim3(64, 8, 1), 256, 0, stream>>>(q, k, v, kmem0, vmem0, idxb,
                                                    AO + (size_t)SZ, 1, 4096);
    gemm_mfma<<<dim3(8, 32, 1), 256, 0, stream>>>(AO, Wo, Wo, Wo, Wo, G, G, G, G, -1);
    combine_kernel<<<2048, 256, 0, stream>>>(G, wg, bo, (float*)d_out);
}

// Round 4
// 982.505 us; speedup vs baseline: 1.2425x; 1.0161x over previous
//
#include <hip/hip_runtime.h>
#include <float.h>
#include <math.h>

// ---------------------------------------------------------------------------
// MABlock: q/k/v/w projections -> attn over batch keys -> FAISS-style exact
// top-8 retrieval from FIFO memory -> attn over retrieved keys -> Wo + gate.
//
// Round 5 (resubmit after infra failure; code audited for hang/crash paths):
//  - split_pack rewritten on v_cvt_pk_bf16_f32 (~3x fewer VALU ops); used by
//    gemm, search and attn staging.
//  - attn: V ownership d = part+8u -> V^T writes hit all 32 banks (2-way
//    dword pairs only, free); V loaded as 8 scalar dwords (L2-resident).
//  - attn: both attn passes merged into ONE launch, and the 128-chunk gather
//    pass split into two 64-chunk halves with online-softmax partials
//    (unnorm O, m, l) merged by combine2_kernel -> 1536 blocks (6/CU launch,
//    4/CU sustained) instead of 512 (2/CU).
// ---------------------------------------------------------------------------

#define DIN   1024
#define NHEADS 16
#define HD    64
#define NB    4
#define NSEQ  512
#define BN    2048          // NB*NSEQ
#define MEMN  32768
#define OLDN  30720         // MEMN - BN
#define IPQ   8
#define ATT_SCALE 0.125f
#define SZ    (BN * DIN)    // 2097152 floats

typedef __attribute__((ext_vector_type(4))) float floatx4;
typedef __attribute__((ext_vector_type(8))) short short8;

__device__ __forceinline__ unsigned short f2bf(float f) {
    unsigned int u = __float_as_uint(f);
    return (unsigned short)((u + 0x7FFFu + ((u >> 16) & 1u)) >> 16);
}
__device__ __forceinline__ float bf2f(unsigned short s) {
    return __uint_as_float(((unsigned int)s) << 16);
}
// packed fp32->bf16 RNE: lo16 = bf16(a), hi16 = bf16(b)
__device__ __forceinline__ unsigned cvt_pk_bf16(float a, float b) {
    unsigned r;
    asm("v_cvt_pk_bf16_f32 %0, %1, %2" : "=v"(r) : "v"(a), "v"(b));
    return r;
}
__device__ __forceinline__ void split_pack(float4 a, float4 b, short8 &hi, short8 &lo) {
    float v[8] = {a.x, a.y, a.z, a.w, b.x, b.y, b.z, b.w};
    union { unsigned u[4]; short8 s; } H, L;
#pragma unroll
    for (int j = 0; j < 4; ++j) {
        unsigned h = cvt_pk_bf16(v[2 * j], v[2 * j + 1]);
        float r0 = v[2 * j]     - __uint_as_float(h << 16);
        float r1 = v[2 * j + 1] - __uint_as_float(h & 0xFFFF0000u);
        H.u[j] = h;
        L.u[j] = cvt_pk_bf16(r0, r1);
    }
    hi = H.s; lo = L.s;
}
__device__ __forceinline__ floatx4 mfma16(short8 a, short8 b, floatx4 c) {
    return __builtin_amdgcn_mfma_f32_16x16x32_bf16(a, b, c, 0, 0, 0);
}

// ---------------------------------------------------------------------------
// init: zero the 16 per-head max-old-norm slots (ws is poisoned 0xAA)
// ---------------------------------------------------------------------------
__global__ void init_kernel(unsigned int* nrm) {
    if (threadIdx.x < NHEADS) nrm[threadIdx.x] = 0u;
}

// ---------------------------------------------------------------------------
// MFMA GEMM: C[z][M][1024] = A[M][1024] @ W[z][1024][1024]^T (NT, k-major).
// 128x128 block tile, 4 waves in 2x2 of 64x64 wave tiles, K-step 32.
// Staging converts fp32 -> split bf16 (hi,lo) into LDS; 4-product mfma.
// C/D layout per 16x16 subtile: row = quad*4+reg, col = l16.
// sigmoidZ: z index that gets a sigmoid epilogue (-1 = none).
// ---------------------------------------------------------------------------
__global__ __launch_bounds__(256) void gemm_mfma(
    const float* __restrict__ A,
    const float* __restrict__ W0, const float* __restrict__ W1,
    const float* __restrict__ W2, const float* __restrict__ W3,
    float* __restrict__ C0, float* __restrict__ C1,
    float* __restrict__ C2, float* __restrict__ C3,
    int sigmoidZ)
{
    __shared__ short Ahi_s[128 * 32];
    __shared__ short Alo_s[128 * 32];
    __shared__ short Bhi_s[128 * 32];
    __shared__ short Blo_s[128 * 32];

    int z = blockIdx.z;
    const float* W = (z == 0) ? W0 : (z == 1) ? W1 : (z == 2) ? W2 : W3;
    float* C = (z == 0) ? C0 : (z == 1) ? C1 : (z == 2) ? C2 : C3;

    int tid = threadIdx.x;
    int wv = tid >> 6, lane = tid & 63, quad = lane >> 4, l16 = lane & 15;
    int row0 = blockIdx.y * 128, col0 = blockIdx.x * 128;
    int wm = (wv >> 1) * 64, wn = (wv & 1) * 64;

    floatx4 zero4 = {0.f, 0.f, 0.f, 0.f};
    floatx4 acc[4][4];
#pragma unroll
    for (int i = 0; i < 4; ++i)
#pragma unroll
        for (int j = 0; j < 4; ++j) acc[i][j] = zero4;

    for (int kk = 0; kk < DIN; kk += 32) {
        __syncthreads();
        // stage 128x32 of A and W, split fp32 -> bf16 hi/lo
#pragma unroll
        for (int p = 0; p < 2; ++p) {
            int g = tid * 2 + p;              // 8-float group, 0..511
            int row = g >> 2, cc = (g & 3) * 8;
            const float* ap = A + (size_t)(row0 + row) * DIN + kk + cc;
            float4 a0 = *(const float4*)ap;
            float4 a1 = *(const float4*)(ap + 4);
            short8 h8, l8;
            split_pack(a0, a1, h8, l8);
            *(short8*)&Ahi_s[g * 8] = h8;
            *(short8*)&Alo_s[g * 8] = l8;
            const float* bp = W + (size_t)(col0 + row) * DIN + kk + cc;
            float4 b0 = *(const float4*)bp;
            float4 b1 = *(const float4*)(bp + 4);
            split_pack(b0, b1, h8, l8);
            *(short8*)&Bhi_s[g * 8] = h8;
            *(short8*)&Blo_s[g * 8] = l8;
        }
        __syncthreads();

        short8 ah[4], al[4], bh[4], bl[4];
#pragma unroll
        for (int t = 0; t < 4; ++t) {
            int ar = (wm + t * 16 + l16) * 32 + quad * 8;
            int br = (wn + t * 16 + l16) * 32 + quad * 8;
            ah[t] = *(const short8*)&Ahi_s[ar];
            al[t] = *(const short8*)&Alo_s[ar];
            bh[t] = *(const short8*)&Bhi_s[br];
            bl[t] = *(const short8*)&Blo_s[br];
        }
#pragma unroll
        for (int tm = 0; tm < 4; ++tm)
#pragma unroll
            for (int tn = 0; tn < 4; ++tn) {
                floatx4 c = acc[tm][tn];
                c = mfma16(al[tm], bl[tn], c);
                c = mfma16(al[tm], bh[tn], c);
                c = mfma16(ah[tm], bl[tn], c);
                c = mfma16(ah[tm], bh[tn], c);
                acc[tm][tn] = c;
            }
    }

    bool sig = (sigmoidZ == z);
#pragma unroll
    for (int tm = 0; tm < 4; ++tm)
#pragma unroll
        for (int tn = 0; tn < 4; ++tn)
#pragma unroll
            for (int r = 0; r < 4; ++r) {
                int row = row0 + wm + tm * 16 + quad * 4 + r;
                int col = col0 + wn + tn * 16 + l16;
                float vv = acc[tm][tn][r];
                if (sig) vv = 1.f / (1.f + __expf(-vv));
                C[(size_t)row * DIN + col] = vv;
            }
}

// ---------------------------------------------------------------------------
// per-head max L2 norm over the 30720 surviving old memory keys
// grid (30, 16), 256 threads; 16 lanes per row.
// ---------------------------------------------------------------------------
__global__ __launch_bounds__(256) void oldnorm_kernel(
    const float* __restrict__ kmem0, unsigned int* __restrict__ nrm)
{
    int h = blockIdx.y;
    int c0 = blockIdx.x * 1024;
    int part = threadIdx.x & 15, rg = threadIdx.x >> 4;
    const float* base = kmem0 + ((size_t)h * MEMN + BN) * HD;
    float mx = 0.f;
    for (int it = 0; it < 64; ++it) {
        int row = c0 + it * 16 + rg;
        float4 vv = *(const float4*)(base + (size_t)row * HD + part * 4);
        float s = vv.x * vv.x + vv.y * vv.y + vv.z * vv.z + vv.w * vv.w;
#pragma unroll
        for (int o = 1; o < 16; o <<= 1) s += __shfl_xor(s, o, 16);
        mx = fmaxf(mx, s);
    }
    __shared__ float red[256];
    red[threadIdx.x] = mx;
    __syncthreads();
    for (int st = 128; st > 0; st >>= 1) {
        if (threadIdx.x < st) red[threadIdx.x] = fmaxf(red[threadIdx.x], red[threadIdx.x + st]);
        __syncthreads();
    }
    if (threadIdx.x == 0) atomicMax(nrm + h, __float_as_uint(sqrtf(red[0])));
}

// ---------------------------------------------------------------------------
// search (MFMA): per (h, 64-query block) exact top-8 over the 2048 new keys.
// 4 waves x 16 queries. Per 32-key chunk: stage K hi/lo bf16 in LDS, S = QK^T
// via 3-product split-bf16 mfma, per-lane top-8 lists, width-16 merge
// (val desc, idx asc = top_k). Bound check -> exact MFMA scan of old memory.
// ---------------------------------------------------------------------------
__device__ __forceinline__ void insert_top8(float (&tv)[8], int (&ti)[8], float v, int id) {
    if (v < tv[7] || (v == tv[7] && id > ti[7])) return;
    tv[7] = v; ti[7] = id;
#pragma unroll
    for (int s = 7; s > 0; --s) {
        bool sw = (tv[s] > tv[s - 1]) || (tv[s] == tv[s - 1] && ti[s] < ti[s - 1]);
        if (sw) {
            float fv = tv[s]; tv[s] = tv[s - 1]; tv[s - 1] = fv;
            int iv = ti[s]; ti[s] = ti[s - 1]; ti[s - 1] = iv;
        }
    }
}

__global__ __launch_bounds__(256, 2) void search_kernel(
    const float* __restrict__ q, const float* __restrict__ knew,
    const float* __restrict__ kmem0, const unsigned int* __restrict__ nrm,
    int* __restrict__ idxOut)
{
    __shared__ short Khi[32 * 72];
    __shared__ short Klo[32 * 72];
    __shared__ int sflag;
    int tid = threadIdx.x;
    int qt = blockIdx.x, h = blockIdx.y;
    int wv = tid >> 6, lane = tid & 63, quad = lane >> 4, l16 = lane & 15;
    if (tid == 0) sflag = 0;

    // persistent Q fragments (A-operand: row=l16, k=quad*8+j, step st*32)
    short8 qhi[2], qlo[2];
    float qn2;   // |q_row(l16)|^2, replicated across quads after reduce
    {
        int qrow = qt * 64 + wv * 16 + l16;
        const float* qp = q + (size_t)qrow * DIN + h * HD;
        float sq = 0.f;
#pragma unroll
        for (int st = 0; st < 2; ++st) {
            float4 a = *(const float4*)(qp + st * 32 + quad * 8);
            float4 c = *(const float4*)(qp + st * 32 + quad * 8 + 4);
            sq += a.x * a.x + a.y * a.y + a.z * a.z + a.w * a.w
                + c.x * c.x + c.y * c.y + c.z * c.z + c.w * c.w;
            split_pack(a, c, qhi[st], qlo[st]);
        }
        sq += __shfl_xor(sq, 16);   // reduce over quad bit0
        sq += __shfl_xor(sq, 32);   // reduce over quad bit1
        qn2 = sq;
    }

    float tv[4][8]; int ti[4][8];
#pragma unroll
    for (int r = 0; r < 4; ++r)
#pragma unroll
        for (int s = 0; s < 8; ++s) { tv[r][s] = -FLT_MAX; ti[r][s] = 0x7FFFFFFF; }

    // ---- phase A: 2048 new keys, 64 chunks of 32 ----
    for (int ch = 0; ch < 64; ++ch) {
        __syncthreads();
        {   // stage 32 K rows, split fp32 -> bf16 hi/lo
            int key = tid >> 3, part = tid & 7;
            const float* kr = knew + (size_t)(ch * 32 + key) * DIN + h * HD;
            float4 ka = *(const float4*)(kr + part * 8);
            float4 kb = *(const float4*)(kr + part * 8 + 4);
            short8 kh8, kl8;
            split_pack(ka, kb, kh8, kl8);
            *(short8*)&Khi[key * 72 + part * 8] = kh8;
            *(short8*)&Klo[key * 72 + part * 8] = kl8;
        }
        __syncthreads();

        short8 kh00 = *(const short8*)&Khi[l16 * 72 + quad * 8];
        short8 kh01 = *(const short8*)&Khi[l16 * 72 + 32 + quad * 8];
        short8 kl00 = *(const short8*)&Klo[l16 * 72 + quad * 8];
        short8 kl01 = *(const short8*)&Klo[l16 * 72 + 32 + quad * 8];
        short8 kh10 = *(const short8*)&Khi[(16 + l16) * 72 + quad * 8];
        short8 kh11 = *(const short8*)&Khi[(16 + l16) * 72 + 32 + quad * 8];
        short8 kl10 = *(const short8*)&Klo[(16 + l16) * 72 + quad * 8];
        short8 kl11 = *(const short8*)&Klo[(16 + l16) * 72 + 32 + quad * 8];
        floatx4 zero4 = {0.f, 0.f, 0.f, 0.f};
        floatx4 s0 = zero4, s1 = zero4;
        s0 = mfma16(qhi[0], kh00, s0); s0 = mfma16(qhi[1], kh01, s0);
        s0 = mfma16(qlo[0], kh00, s0); s0 = mfma16(qlo[1], kh01, s0);
        s0 = mfma16(qhi[0], kl00, s0); s0 = mfma16(qhi[1], kl01, s0);
        s1 = mfma16(qhi[0], kh10, s1); s1 = mfma16(qhi[1], kh11, s1);
        s1 = mfma16(qlo[0], kh10, s1); s1 = mfma16(qlo[1], kh11, s1);
        s1 = mfma16(qhi[0], kl10, s1); s1 = mfma16(qhi[1], kl11, s1);

        int base = OLDN + ch * 32;
#pragma unroll
        for (int r = 0; r < 4; ++r) {
            insert_top8(tv[r], ti[r], s0[r], base + l16);
            insert_top8(tv[r], ti[r], s1[r], base + 16 + l16);
        }
    }

    // ---- merge #1 across the 16 lanes of each quad ----
    float val8[4], keepv[4];
    int keepi[4];
#pragma unroll
    for (int rr = 0; rr < 4; ++rr) { keepv[rr] = -FLT_MAX; keepi[rr] = 0x7FFFFFFF; val8[rr] = -FLT_MAX; }
#pragma unroll
    for (int rr = 0; rr < 4; ++rr) {
#pragma unroll
        for (int m = 0; m < 8; ++m) {
            float cv = tv[rr][0]; int ci = ti[rr][0];
#pragma unroll
            for (int o = 1; o < 16; o <<= 1) {
                float ov = __shfl_xor(cv, o, 16);
                int oi = __shfl_xor(ci, o, 16);
                if (ov > cv || (ov == cv && oi < ci)) { cv = ov; ci = oi; }
            }
            if (tv[rr][0] == cv && ti[rr][0] == ci) {
#pragma unroll
                for (int s = 0; s < 7; ++s) { tv[rr][s] = tv[rr][s + 1]; ti[rr][s] = ti[rr][s + 1]; }
                tv[rr][7] = -FLT_MAX; ti[rr][7] = 0x7FFFFFFF;
            }
            if (l16 == m) { keepv[rr] = cv; keepi[rr] = ci; }
            if (l16 == 0)
                idxOut[((size_t)h * BN + qt * 64 + wv * 16 + quad * 4 + rr) * IPQ + m] = ci;
            val8[rr] = cv;
        }
    }

    // ---- bound check: can any old key enter the top-8? ----
    float oldMax = __uint_as_float(nrm[h]);
    bool need = false;
#pragma unroll
    for (int rr = 0; rr < 4; ++rr) {
        float bq = __shfl(qn2, quad * 4 + rr, 16);
        float bnd = sqrtf(bq) * oldMax * 1.0001f + 1e-5f;
        if (bnd >= val8[rr]) need = true;
    }
    if (need) sflag = 1;
    __syncthreads();

    if (sflag) {
        // rebuild per-lane lists: lanes l16<8 hold winner m=l16, rest empty
#pragma unroll
        for (int rr = 0; rr < 4; ++rr) {
            tv[rr][0] = (l16 < 8) ? keepv[rr] : -FLT_MAX;
            ti[rr][0] = (l16 < 8) ? keepi[rr] : 0x7FFFFFFF;
#pragma unroll
            for (int s = 1; s < 8; ++s) { tv[rr][s] = -FLT_MAX; ti[rr][s] = 0x7FFFFFFF; }
        }
        // exact scan of the 30720 surviving old keys, 960 chunks of 32
        for (int ch = 0; ch < 960; ++ch) {
            __syncthreads();
            {
                int key = tid >> 3, part = tid & 7;
                const float* kr = kmem0 + ((size_t)h * MEMN + BN + ch * 32 + key) * HD;
                float4 ka = *(const float4*)(kr + part * 8);
                float4 kb = *(const float4*)(kr + part * 8 + 4);
                short8 kh8, kl8;
                split_pack(ka, kb, kh8, kl8);
                *(short8*)&Khi[key * 72 + part * 8] = kh8;
                *(short8*)&Klo[key * 72 + part * 8] = kl8;
            }
            __syncthreads();

            short8 kh00 = *(const short8*)&Khi[l16 * 72 + quad * 8];
            short8 kh01 = *(const short8*)&Khi[l16 * 72 + 32 + quad * 8];
            short8 kl00 = *(const short8*)&Klo[l16 * 72 + quad * 8];
            short8 kl01 = *(const short8*)&Klo[l16 * 72 + 32 + quad * 8];
            short8 kh10 = *(const short8*)&Khi[(16 + l16) * 72 + quad * 8];
            short8 kh11 = *(const short8*)&Khi[(16 + l16) * 72 + 32 + quad * 8];
            short8 kl10 = *(const short8*)&Klo[(16 + l16) * 72 + quad * 8];
            short8 kl11 = *(const short8*)&Klo[(16 + l16) * 72 + 32 + quad * 8];
            floatx4 zero4 = {0.f, 0.f, 0.f, 0.f};
            floatx4 s0 = zero4, s1 = zero4;
            s0 = mfma16(qhi[0], kh00, s0); s0 = mfma16(qhi[1], kh01, s0);
            s0 = mfma16(qlo[0], kh00, s0); s0 = mfma16(qlo[1], kh01, s0);
            s0 = mfma16(qhi[0], kl00, s0); s0 = mfma16(qhi[1], kl01, s0);
            s1 = mfma16(qhi[0], kh10, s1); s1 = mfma16(qhi[1], kh11, s1);
            s1 = mfma16(qlo[0], kh10, s1); s1 = mfma16(qlo[1], kh11, s1);
            s1 = mfma16(qhi[0], kl10, s1); s1 = mfma16(qhi[1], kl11, s1);

            int base = ch * 32;
#pragma unroll
            for (int r = 0; r < 4; ++r) {
                insert_top8(tv[r], ti[r], s0[r], base + l16);
                insert_top8(tv[r], ti[r], s1[r], base + 16 + l16);
            }
        }
        // merge #2 (final)
#pragma unroll
        for (int rr = 0; rr < 4; ++rr) {
#pragma unroll
            for (int m = 0; m < 8; ++m) {
                float cv = tv[rr][0]; int ci = ti[rr][0];
#pragma unroll
                for (int o = 1; o < 16; o <<= 1) {
                    float ov = __shfl_xor(cv, o, 16);
                    int oi = __shfl_xor(ci, o, 16);
                    if (ov > cv || (ov == cv && oi < ci)) { cv = ov; ci = oi; }
                }
                if (tv[rr][0] == cv && ti[rr][0] == ci) {
#pragma unroll
                    for (int s = 0; s < 7; ++s) { tv[rr][s] = tv[rr][s + 1]; ti[rr][s] = ti[rr][s + 1]; }
                    tv[rr][7] = -FLT_MAX; ti[rr][7] = 0x7FFFFFFF;
                }
                if (l16 == 0)
                    idxOut[((size_t)h * BN + qt * 64 + wv * 16 + quad * 4 + rr) * IPQ + m] = ci;
            }
        }
    }
}

// ---------------------------------------------------------------------------
// MFMA flash attention, merged. Grid (pair=h*4+b, mode, qt):
//   mode 0: batch attn over 512 new keys (chunks 0..15), normalized -> AO.
//   mode 1: gather attn chunks 0..63  -> unnorm O to AO+SZ, (m,l) to mlbuf.
//   mode 2: gather attn chunks 64..127-> unnorm O to G,     (m,l) to mlbuf.
// flat%8 = pair%8 keeps all blocks of one (h,b) on one XCD for L2 reuse.
// Per 32-key chunk: gather loads register-prefetched one chunk ahead;
// K staged b128 (split-bf16); V staged with d=part+8u ownership (scalar
// loads, conflict-free transposed b16 writes); barriers are raw s_barrier +
// lgkmcnt(0) so prefetched global loads stay in flight. S = QK^T 3-product,
// per-wave online softmax, P via per-wave LDS round-trip, O += P*Vhi + P*Vlo.
// ---------------------------------------------------------------------------
__global__ __launch_bounds__(256, 2) void attn_kernel(
    const float* __restrict__ q, const float* __restrict__ knew,
    const float* __restrict__ vnew, const float* __restrict__ kmem0,
    const float* __restrict__ vmem0, const int* __restrict__ idxb,
    float* __restrict__ AO, float* __restrict__ G)
{
    __shared__ short Khi[32 * 72];
    __shared__ short Klo[32 * 72];
    __shared__ short Vthi[64 * 40];
    __shared__ short Vtlo[64 * 40];
    __shared__ short Pbuf[4 * 16 * 40];
    int tid = threadIdx.x;
    int pair = blockIdx.x, mode = blockIdx.y, qt = blockIdx.z;
    int h = pair >> 2, b = pair & 3;
    int wv = tid >> 6, lane = tid & 63, quad = lane >> 4, l16 = lane & 15;

    // persistent Q fragments (A-operand layout: row=l16, k=quad*8+j, step*32)
    short8 qhi[2], qlo[2];
    {
        int qrow = b * NSEQ + qt * 64 + wv * 16 + l16;
        const float* qp = q + (size_t)qrow * DIN + h * HD;
#pragma unroll
        for (int st = 0; st < 2; ++st) {
            float4 a = *(const float4*)(qp + st * 32 + quad * 8);
            float4 c = *(const float4*)(qp + st * 32 + quad * 8 + 4);
            split_pack(a, c, qhi[st], qlo[st]);
        }
    }
    floatx4 zero4 = {0.f, 0.f, 0.f, 0.f};
    floatx4 Oacc[4];
#pragma unroll
    for (int t = 0; t < 4; ++t) Oacc[t] = zero4;
    float mrow[4], lrow[4];
#pragma unroll
    for (int r = 0; r < 4; ++r) { mrow[r] = -3.0e38f; lrow[r] = 0.f; }

    int key = tid >> 3, part = tid & 7;
    float4 ka, kb;                        // prefetched K row registers
    float vv[8];                          // prefetched V dims part+8u
    auto gload = [&](int chl) {
        const float *kr, *vr;
        if (mode == 0) {
            int row = b * NSEQ + chl * 32 + key;
            kr = knew + (size_t)row * DIN + h * HD;
            vr = vnew + (size_t)row * DIN + h * HD;
        } else {
            int J = chl * 32 + key;
            int mi = idxb[((size_t)h * BN + b * NSEQ + (J >> 3)) * IPQ + (J & 7)];
            if (mi < OLDN) {
                kr = kmem0 + ((size_t)h * MEMN + BN + mi) * HD;
                vr = vmem0 + ((size_t)h * MEMN + BN + mi) * HD;
            } else {
                kr = knew + (size_t)(mi - OLDN) * DIN + h * HD;
                vr = vnew + (size_t)(mi - OLDN) * DIN + h * HD;
            }
        }
        ka = *(const float4*)(kr + part * 8);
        kb = *(const float4*)(kr + part * 8 + 4);
#pragma unroll
        for (int u = 0; u < 8; ++u) vv[u] = vr[part + 8 * u];
    };

    int ch0 = (mode == 2) ? 64 : 0;
    int ch1 = (mode == 0) ? 16 : ((mode == 1) ? 64 : 128);
    gload(ch0);                           // prologue prefetch
    for (int ch = ch0; ch < ch1; ++ch) {
        // barrier #1: previous chunk's LDS reads done before overwrite.
        // LDS-only dependency -> lgkmcnt is sufficient; vmcnt (prefetched
        // gather loads) intentionally stays in flight.
        asm volatile("s_waitcnt lgkmcnt(0)" ::: "memory");
        __builtin_amdgcn_s_barrier();

        { // stage K row (b128) + V dims (scalar transposed, conflict-free)
            short8 kh8, kl8;
            split_pack(ka, kb, kh8, kl8);
            *(short8*)&Khi[key * 72 + part * 8] = kh8;
            *(short8*)&Klo[key * 72 + part * 8] = kl8;
#pragma unroll
            for (int u = 0; u < 8; u += 2) {
                unsigned hh = cvt_pk_bf16(vv[u], vv[u + 1]);
                float r0 = vv[u]     - __uint_as_float(hh << 16);
                float r1 = vv[u + 1] - __uint_as_float(hh & 0xFFFF0000u);
                unsigned ll = cvt_pk_bf16(r0, r1);
                Vthi[(part + 8 * u) * 40 + key]       = (short)(hh & 0xFFFF);
                Vthi[(part + 8 * (u + 1)) * 40 + key] = (short)(hh >> 16);
                Vtlo[(part + 8 * u) * 40 + key]       = (short)(ll & 0xFFFF);
                Vtlo[(part + 8 * (u + 1)) * 40 + key] = (short)(ll >> 16);
            }
        }
        if (ch + 1 < ch1) gload(ch + 1); // issue next gather; hides under MFMA

        // barrier #2: staging visible to all waves (again lgkmcnt only)
        asm volatile("s_waitcnt lgkmcnt(0)" ::: "memory");
        __builtin_amdgcn_s_barrier();

        // S = Q K^T (two 16-key col tiles), split-bf16 3-product
        short8 kh00 = *(const short8*)&Khi[(l16) * 72 + 0 * 32 + quad * 8];
        short8 kh01 = *(const short8*)&Khi[(l16) * 72 + 1 * 32 + quad * 8];
        short8 kl00 = *(const short8*)&Klo[(l16) * 72 + 0 * 32 + quad * 8];
        short8 kl01 = *(const short8*)&Klo[(l16) * 72 + 1 * 32 + quad * 8];
        short8 kh10 = *(const short8*)&Khi[(16 + l16) * 72 + 0 * 32 + quad * 8];
        short8 kh11 = *(const short8*)&Khi[(16 + l16) * 72 + 1 * 32 + quad * 8];
        short8 kl10 = *(const short8*)&Klo[(16 + l16) * 72 + 0 * 32 + quad * 8];
        short8 kl11 = *(const short8*)&Klo[(16 + l16) * 72 + 1 * 32 + quad * 8];
        floatx4 s0 = zero4, s1 = zero4;
        s0 = mfma16(qhi[0], kh00, s0); s0 = mfma16(qhi[1], kh01, s0);
        s0 = mfma16(qlo[0], kh00, s0); s0 = mfma16(qlo[1], kh01, s0);
        s0 = mfma16(qhi[0], kl00, s0); s0 = mfma16(qhi[1], kl01, s0);
        s1 = mfma16(qhi[0], kh10, s1); s1 = mfma16(qhi[1], kh11, s1);
        s1 = mfma16(qlo[0], kh10, s1); s1 = mfma16(qlo[1], kh11, s1);
        s1 = mfma16(qhi[0], kl10, s1); s1 = mfma16(qhi[1], kl11, s1);

        // online softmax (rows = quad*4+r, cols spread over 16 lanes)
        float cm[4], alpha[4], p0[4], p1[4], rs[4];
#pragma unroll
        for (int r = 0; r < 4; ++r) cm[r] = fmaxf(s0[r], s1[r]) * ATT_SCALE;
#pragma unroll
        for (int o = 1; o < 16; o <<= 1) {
#pragma unroll
            for (int r = 0; r < 4; ++r) cm[r] = fmaxf(cm[r], __shfl_xor(cm[r], o, 16));
        }
#pragma unroll
        for (int r = 0; r < 4; ++r) {
            float mn = fmaxf(mrow[r], cm[r]);
            alpha[r] = __expf(mrow[r] - mn);
            p0[r] = __expf(s0[r] * ATT_SCALE - mn);
            p1[r] = __expf(s1[r] * ATT_SCALE - mn);
            mrow[r] = mn;
            rs[r] = p0[r] + p1[r];
        }
#pragma unroll
        for (int o = 1; o < 16; o <<= 1) {
#pragma unroll
            for (int r = 0; r < 4; ++r) rs[r] += __shfl_xor(rs[r], o, 16);
        }
#pragma unroll
        for (int r = 0; r < 4; ++r) {
            lrow[r] = lrow[r] * alpha[r] + rs[r];
            unsigned pw = cvt_pk_bf16(p0[r], p1[r]);
            Pbuf[(wv * 16 + quad * 4 + r) * 40 + l16]      = (short)(pw & 0xFFFF);
            Pbuf[(wv * 16 + quad * 4 + r) * 40 + 16 + l16] = (short)(pw >> 16);
        }
#pragma unroll
        for (int t = 0; t < 4; ++t)
#pragma unroll
            for (int r = 0; r < 4; ++r) Oacc[t][r] *= alpha[r];
        // Pbuf round-trip is per-wave (both sides indexed by wv): no barrier.
        // Vt reads are protected by barrier #2; compiler orders Pbuf
        // write->read via lgkmcnt (may-alias LDS).

        short8 pf = *(const short8*)&Pbuf[(wv * 16 + l16) * 40 + quad * 8];
#pragma unroll
        for (int t = 0; t < 4; ++t) {
            short8 vh = *(const short8*)&Vthi[(t * 16 + l16) * 40 + quad * 8];
            short8 vl = *(const short8*)&Vtlo[(t * 16 + l16) * 40 + quad * 8];
            floatx4 o = Oacc[t];
            o = mfma16(pf, vh, o);
            o = mfma16(pf, vl, o);
            Oacc[t] = o;
        }
    }
    // epilogue
    if (mode == 0) {
        // normalized write to AO (rows = quad*4+r, cols = t*16+l16)
#pragma unroll
        for (int t = 0; t < 4; ++t)
#pragma unroll
            for (int r = 0; r < 4; ++r) {
                int qrow = b * NSEQ + qt * 64 + wv * 16 + quad * 4 + r;
                AO[(size_t)qrow * DIN + h * HD + t * 16 + l16] = Oacc[t][r] / lrow[r];
            }
    } else {
        float* ob = (mode == 1) ? (AO + (size_t)SZ) : G;
        float* mlbuf = G + (size_t)SZ + ((size_t)(mode - 1) * NHEADS + h) * BN * 2;
#pragma unroll
        for (int t = 0; t < 4; ++t)
#pragma unroll
            for (int r = 0; r < 4; ++r) {
                int qrow = b * NSEQ + qt * 64 + wv * 16 + quad * 4 + r;
                ob[(size_t)qrow * DIN + h * HD + t * 16 + l16] = Oacc[t][r];
            }
        if (l16 == 0) {
#pragma unroll
            for (int r = 0; r < 4; ++r) {
                int qrow = b * NSEQ + qt * 64 + wv * 16 + quad * 4 + r;
                float2 mlv = {mrow[r], lrow[r]};
                *(float2*)&mlbuf[(size_t)qrow * 2] = mlv;
            }
        }
    }
}

// ---------------------------------------------------------------------------
// combine2: merge the two gather-attn halves' online-softmax partials.
// O0 (AO+SZ, in place), O1 (G), ml (G+SZ): [part][h][2048][(m,l)].
// ---------------------------------------------------------------------------
__global__ __launch_bounds__(256) void combine2_kernel(
    float* __restrict__ O0, const float* __restrict__ O1,
    const float* __restrict__ ml)
{
    int g = blockIdx.x * 256 + threadIdx.x;   // f4 index, SZ/4 total
    int row = g >> 8;                         // 256 f4 per 1024-wide row
    int h = (g >> 4) & 15;                    // 16 f4 per head slice
    float2 ml0 = *(const float2*)&ml[((size_t)h * BN + row) * 2];
    float2 ml1 = *(const float2*)&ml[(((size_t)NHEADS + h) * BN + row) * 2];
    float m = fmaxf(ml0.x, ml1.x);
    float a0 = __expf(ml0.x - m), a1 = __expf(ml1.x - m);
    float inv = 1.f / (ml0.y * a0 + ml1.y * a1);
    float4 o0 = ((const float4*)O0)[g];
    float4 o1 = ((const float4*)O1)[g];
    float4 o;
    o.x = (o0.x * a0 + o1.x * a1) * inv;
    o.y = (o0.y * a0 + o1.y * a1) * inv;
    o.z = (o0.z * a0 + o1.z * a1) * inv;
    o.w = (o0.w * a0 + o1.w * a1) * inv;
    ((float4*)O0)[g] = o;
}

// ---------------------------------------------------------------------------
// out = w*G1 + (1-w)*G2 + bo   (bias factors out of the gate)
// ---------------------------------------------------------------------------
__global__ __launch_bounds__(256) void combine_kernel(
    const float* __restrict__ G, const float* __restrict__ wg,
    const float* __restrict__ bo, float* __restrict__ out)
{
    int gid = blockIdx.x * 256 + threadIdx.x;     // f4 index, 524288 total
    float4 g1 = ((const float4*)G)[gid];
    float4 g2 = ((const float4*)G)[gid + (SZ / 4)];
    float4 w4 = ((const float4*)wg)[gid];
    float4 b4 = ((const float4*)bo)[gid & (DIN / 4 - 1)];
    float4 o;
    o.x = w4.x * g1.x + (1.f - w4.x) * g2.x + b4.x;
    o.y = w4.y * g1.y + (1.f - w4.y) * g2.y + b4.y;
    o.z = w4.z * g1.z + (1.f - w4.z) * g2.z + b4.z;
    o.w = w4.w * g1.w + (1.f - w4.w) * g2.w + b4.w;
    ((float4*)out)[gid] = o;
}

// ---------------------------------------------------------------------------
extern "C" void kernel_launch(void* const* d_in, const int* in_sizes, int n_in,
                              void* d_out, int out_size, void* d_ws, size_t ws_size,
                              hipStream_t stream)
{
    (void)in_sizes; (void)n_in; (void)out_size; (void)ws_size;
    const float* x     = (const float*)d_in[0];
    const float* Wq    = (const float*)d_in[1];
    const float* Wk    = (const float*)d_in[2];
    const float* Wv    = (const float*)d_in[3];
    const float* Ww    = (const float*)d_in[4];
    const float* Wo    = (const float*)d_in[5];
    const float* bo    = (const float*)d_in[6];
    const float* kmem0 = (const float*)d_in[7];
    const float* vmem0 = (const float*)d_in[8];

    float* ws = (float*)d_ws;
    float* q  = ws;
    float* k  = ws + (size_t)SZ;
    float* v  = ws + (size_t)2 * SZ;
    float* wg = ws + (size_t)3 * SZ;
    float* AO = ws + (size_t)4 * SZ;          // 2*SZ (rows 0..2047 = a, 2048.. = a_m)
    float* G  = ws + (size_t)6 * SZ;          // 2*SZ (attn scratch, then gemm2 out)
    int* idxb = (int*)(ws + (size_t)8 * SZ);  // 16*2048*8
    unsigned int* nrm = (unsigned int*)(ws + (size_t)8 * SZ + NHEADS * BN * IPQ);

    init_kernel<<<1, 64, 0, stream>>>(nrm);
    gemm_mfma<<<dim3(8, 16, 4), 256, 0, stream>>>(x, Wq, Wk, Wv, Ww, q, k, v, wg, 3);
    oldnorm_kernel<<<dim3(30, 16), 256, 0, stream>>>(kmem0, nrm);
    search_kernel<<<dim3(32, 16), 256, 0, stream>>>(q, k, kmem0, nrm, idxb);
    attn_kernel<<<dim3(64, 3, 8), 256, 0, stream>>>(q, k, v, kmem0, vmem0, idxb, AO, G);
    combine2_kernel<<<2048, 256, 0, stream>>>(AO + (size_t)SZ, G, G + (size_t)SZ);
    gemm_mfma<<<dim3(8, 32, 1), 256, 0, stream>>>(AO, Wo, Wo, Wo, Wo, G, G, G, G, -1);
    combine_kernel<<<2048, 256, 0, stream>>>(G, wg, bo, (float*)d_out);
}

// Round 5
// 940.515 us; speedup vs baseline: 1.2979x; 1.0446x over previous
//
#include <hip/hip_runtime.h>
#include <float.h>
#include <math.h>

// ---------------------------------------------------------------------------
// MABlock: q/k/v/w projections -> attn over batch keys -> FAISS-style exact
// top-8 retrieval from FIFO memory -> attn over retrieved keys -> Wo + gate.
//
// Round 6:
//  - All intermediates stored PRE-SPLIT as packed u32 (bf16hi | bf16lo<<16):
//    x/W/Wo pre-split once; gemm1 emits q/k/v packed; attn emits AO packed.
//    Staging everywhere = load+unpack (~12 VALU vs ~50) and half the bytes.
//  - attn: XCD mapping groups 2 heads per XCD (new-key k/v slices 2MB -> L2
//    resident); idx prefetched 2 chunks ahead, rows 1 chunk ahead (splits the
//    idx->row dependency chain across two compute phases).
//  - search: grid (h, qt) so h%8 picks the XCD (k slice L2-resident).
// ---------------------------------------------------------------------------

#define DIN   1024
#define NHEADS 16
#define HD    64
#define NB    4
#define NSEQ  512
#define BN    2048          // NB*NSEQ
#define MEMN  32768
#define OLDN  30720         // MEMN - BN
#define IPQ   8
#define ATT_SCALE 0.125f
#define SZ    (BN * DIN)    // 2097152 floats

// workspace byte offsets
#define WS_WG_OFF    25165824ull   // 24MB: wg fp32 [2048][1024]
#define WS_AOPK_OFF  33554432ull   // 32MB: AOpk u32 [4096][1024] (16MB)
#define WS_XPK_OFF   33554432ull   // 32MB: xpk u32 (8MB, pre-gemm1 only)
#define WS_WPK_OFF   41943040ull   // 40MB: Wpk u32 x4 (16MB, pre-gemm1 only)
#define WS_GF_OFF    50331648ull   // 48MB: G fp32 [4096][1024] (16MB)
#define WS_IDX_OFF   67108864ull   // 64MB: idx (1MB)
#define WS_ML_OFF    68157440ull   // 65MB: ml partials (1MB)
#define WS_NRM_OFF   69206016ull   // 66MB: nrm (64B)
#define WS_WOPK_OFF  69210112ull   // 66MB+4KB: Wopk u32 (4MB)

typedef __attribute__((ext_vector_type(4))) float floatx4;
typedef __attribute__((ext_vector_type(8))) short short8;

__device__ __forceinline__ unsigned short f2bf(float f) {
    unsigned int u = __float_as_uint(f);
    return (unsigned short)((u + 0x7FFFu + ((u >> 16) & 1u)) >> 16);
}
__device__ __forceinline__ float bf2f(unsigned short s) {
    return __uint_as_float(((unsigned int)s) << 16);
}
// pack fp32 -> (bf16 hi | bf16 lo<<16), lo = bf16(v - hi)
__device__ __forceinline__ unsigned pack32(float v) {
    unsigned h = f2bf(v);
    unsigned l = f2bf(v - bf2f((unsigned short)h));
    return (h & 0xFFFFu) | (l << 16);
}
// 8 packed u32 -> hi/lo short8 fragments
__device__ __forceinline__ void unpack8(uint4 a, uint4 b, short8 &hi, short8 &lo) {
    unsigned p[8] = {a.x, a.y, a.z, a.w, b.x, b.y, b.z, b.w};
    union { unsigned u[4]; short8 s; } H, L;
#pragma unroll
    for (int j = 0; j < 4; ++j) {
        unsigned e = p[2 * j], o = p[2 * j + 1];
        H.u[j] = (e & 0xFFFFu) | (o << 16);
        L.u[j] = (e >> 16) | (o & 0xFFFF0000u);
    }
    hi = H.s; lo = L.s;
}
__device__ __forceinline__ void unpack8f(float4 fa, float4 fb, short8 &hi, short8 &lo) {
    uint4 a = {__float_as_uint(fa.x), __float_as_uint(fa.y), __float_as_uint(fa.z), __float_as_uint(fa.w)};
    uint4 b = {__float_as_uint(fb.x), __float_as_uint(fb.y), __float_as_uint(fb.z), __float_as_uint(fb.w)};
    unpack8(a, b, hi, lo);
}
// fp32x8 -> split bf16 hi/lo (for fp32 sources: kmem0/vmem0)
__device__ __forceinline__ void split_pack(float4 a, float4 b, short8 &hi, short8 &lo) {
    float v[8] = {a.x, a.y, a.z, a.w, b.x, b.y, b.z, b.w};
    union { unsigned u[4]; short8 s; } H, L;
#pragma unroll
    for (int j = 0; j < 4; ++j) {
        unsigned p0 = pack32(v[2 * j]), p1 = pack32(v[2 * j + 1]);
        H.u[j] = (p0 & 0xFFFFu) | (p1 << 16);
        L.u[j] = (p0 >> 16) | (p1 & 0xFFFF0000u);
    }
    hi = H.s; lo = L.s;
}
__device__ __forceinline__ floatx4 mfma16(short8 a, short8 b, floatx4 c) {
    return __builtin_amdgcn_mfma_f32_16x16x32_bf16(a, b, c, 0, 0, 0);
}

// ---------------------------------------------------------------------------
__global__ void init_kernel(unsigned int* nrm) {
    if (threadIdx.x < NHEADS) nrm[threadIdx.x] = 0u;
}

// ---------------------------------------------------------------------------
// presplit: fp32 -> packed u32 (hi|lo<<16). z picks source; out + z*n4*4.
// ---------------------------------------------------------------------------
__global__ __launch_bounds__(256) void presplit_kernel(
    const float* __restrict__ s0, const float* __restrict__ s1,
    const float* __restrict__ s2, const float* __restrict__ s3,
    unsigned* __restrict__ out, int n4)
{
    int z = blockIdx.y;
    const float* s = (z == 0) ? s0 : (z == 1) ? s1 : (z == 2) ? s2 : s3;
    int i = blockIdx.x * 256 + threadIdx.x;
    float4 v = ((const float4*)s)[i];
    uint4 o = {pack32(v.x), pack32(v.y), pack32(v.z), pack32(v.w)};
    ((uint4*)(out + (size_t)z * n4 * 4))[i] = o;
}

// ---------------------------------------------------------------------------
// MFMA GEMM on packed-u32 inputs: C[z] = A @ B[z]^T (NT, k-major).
// 128x128 tile, 4 waves 2x2, K-step 32. Staging = load packed + unpack.
// z < packN: output packed u32 at OutPk + z*2097152; else fp32 to OutF
// (sigmoid if z == sigmoidZ).
// ---------------------------------------------------------------------------
__global__ __launch_bounds__(256) void gemm_pk(
    const unsigned* __restrict__ Apk,
    const unsigned* __restrict__ B0, const unsigned* __restrict__ B1,
    const unsigned* __restrict__ B2, const unsigned* __restrict__ B3,
    unsigned* __restrict__ OutPk, float* __restrict__ OutF,
    int packN, int sigmoidZ)
{
    __shared__ short Ahi_s[128 * 32];
    __shared__ short Alo_s[128 * 32];
    __shared__ short Bhi_s[128 * 32];
    __shared__ short Blo_s[128 * 32];

    int z = blockIdx.z;
    const unsigned* B = (z == 0) ? B0 : (z == 1) ? B1 : (z == 2) ? B2 : B3;

    int tid = threadIdx.x;
    int wv = tid >> 6, lane = tid & 63, quad = lane >> 4, l16 = lane & 15;
    int row0 = blockIdx.y * 128, col0 = blockIdx.x * 128;
    int wm = (wv >> 1) * 64, wn = (wv & 1) * 64;

    floatx4 zero4 = {0.f, 0.f, 0.f, 0.f};
    floatx4 acc[4][4];
#pragma unroll
    for (int i = 0; i < 4; ++i)
#pragma unroll
        for (int j = 0; j < 4; ++j) acc[i][j] = zero4;

    for (int kk = 0; kk < DIN; kk += 32) {
        __syncthreads();
#pragma unroll
        for (int p = 0; p < 2; ++p) {
            int g = tid * 2 + p;              // 8-elem group, 0..511
            int row = g >> 2, cc = (g & 3) * 8;
            const unsigned* ap = Apk + (size_t)(row0 + row) * DIN + kk + cc;
            short8 h8, l8;
            unpack8(*(const uint4*)ap, *(const uint4*)(ap + 4), h8, l8);
            *(short8*)&Ahi_s[g * 8] = h8;
            *(short8*)&Alo_s[g * 8] = l8;
            const unsigned* bp = B + (size_t)(col0 + row) * DIN + kk + cc;
            unpack8(*(const uint4*)bp, *(const uint4*)(bp + 4), h8, l8);
            *(short8*)&Bhi_s[g * 8] = h8;
            *(short8*)&Blo_s[g * 8] = l8;
        }
        __syncthreads();

        short8 ah[4], al[4], bh[4], bl[4];
#pragma unroll
        for (int t = 0; t < 4; ++t) {
            int ar = (wm + t * 16 + l16) * 32 + quad * 8;
            int br = (wn + t * 16 + l16) * 32 + quad * 8;
            ah[t] = *(const short8*)&Ahi_s[ar];
            al[t] = *(const short8*)&Alo_s[ar];
            bh[t] = *(const short8*)&Bhi_s[br];
            bl[t] = *(const short8*)&Blo_s[br];
        }
#pragma unroll
        for (int tm = 0; tm < 4; ++tm)
#pragma unroll
            for (int tn = 0; tn < 4; ++tn) {
                floatx4 c = acc[tm][tn];
                c = mfma16(al[tm], bl[tn], c);
                c = mfma16(al[tm], bh[tn], c);
                c = mfma16(ah[tm], bl[tn], c);
                c = mfma16(ah[tm], bh[tn], c);
                acc[tm][tn] = c;
            }
    }

    if (z < packN) {
        unsigned* O = OutPk + (size_t)z * 2097152;
#pragma unroll
        for (int tm = 0; tm < 4; ++tm)
#pragma unroll
            for (int tn = 0; tn < 4; ++tn)
#pragma unroll
                for (int r = 0; r < 4; ++r) {
                    int row = row0 + wm + tm * 16 + quad * 4 + r;
                    int col = col0 + wn + tn * 16 + l16;
                    O[(size_t)row * DIN + col] = pack32(acc[tm][tn][r]);
                }
    } else {
        bool sig = (sigmoidZ == z);
#pragma unroll
        for (int tm = 0; tm < 4; ++tm)
#pragma unroll
            for (int tn = 0; tn < 4; ++tn)
#pragma unroll
                for (int r = 0; r < 4; ++r) {
                    int row = row0 + wm + tm * 16 + quad * 4 + r;
                    int col = col0 + wn + tn * 16 + l16;
                    float vv = acc[tm][tn][r];
                    if (sig) vv = 1.f / (1.f + __expf(-vv));
                    OutF[(size_t)row * DIN + col] = vv;
                }
    }
}

// ---------------------------------------------------------------------------
// per-head max L2 norm over the 30720 surviving old memory keys
// ---------------------------------------------------------------------------
__global__ __launch_bounds__(256) void oldnorm_kernel(
    const float* __restrict__ kmem0, unsigned int* __restrict__ nrm)
{
    int h = blockIdx.y;
    int c0 = blockIdx.x * 1024;
    int part = threadIdx.x & 15, rg = threadIdx.x >> 4;
    const float* base = kmem0 + ((size_t)h * MEMN + BN) * HD;
    float mx = 0.f;
    for (int it = 0; it < 64; ++it) {
        int row = c0 + it * 16 + rg;
        float4 vv = *(const float4*)(base + (size_t)row * HD + part * 4);
        float s = vv.x * vv.x + vv.y * vv.y + vv.z * vv.z + vv.w * vv.w;
#pragma unroll
        for (int o = 1; o < 16; o <<= 1) s += __shfl_xor(s, o, 16);
        mx = fmaxf(mx, s);
    }
    __shared__ float red[256];
    red[threadIdx.x] = mx;
    __syncthreads();
    for (int st = 128; st > 0; st >>= 1) {
        if (threadIdx.x < st) red[threadIdx.x] = fmaxf(red[threadIdx.x], red[threadIdx.x + st]);
        __syncthreads();
    }
    if (threadIdx.x == 0) atomicMax(nrm + h, __float_as_uint(sqrtf(red[0])));
}

// ---------------------------------------------------------------------------
// search: grid (h, qt) -> h%8 picks the XCD (per-head k slice L2-resident).
// Per 32-key chunk: stage packed K (unpack to hi/lo), S = QK^T 3-product,
// per-lane top-8, width-16 merge (val desc, idx asc). Bound check ->
// exact MFMA scan of old memory (fp32 split path).
// ---------------------------------------------------------------------------
__device__ __forceinline__ void insert_top8(float (&tv)[8], int (&ti)[8], float v, int id) {
    if (v < tv[7] || (v == tv[7] && id > ti[7])) return;
    tv[7] = v; ti[7] = id;
#pragma unroll
    for (int s = 7; s > 0; --s) {
        bool sw = (tv[s] > tv[s - 1]) || (tv[s] == tv[s - 1] && ti[s] < ti[s - 1]);
        if (sw) {
            float fv = tv[s]; tv[s] = tv[s - 1]; tv[s - 1] = fv;
            int iv = ti[s]; ti[s] = ti[s - 1]; ti[s - 1] = iv;
        }
    }
}

__global__ __launch_bounds__(256, 2) void search_kernel(
    const unsigned* __restrict__ qpk, const unsigned* __restrict__ kpk,
    const float* __restrict__ kmem0, const unsigned int* __restrict__ nrm,
    int* __restrict__ idxOut)
{
    __shared__ short Khi[32 * 72];
    __shared__ short Klo[32 * 72];
    __shared__ int sflag;
    int tid = threadIdx.x;
    int h = blockIdx.x, qt = blockIdx.y;
    int wv = tid >> 6, lane = tid & 63, quad = lane >> 4, l16 = lane & 15;
    if (tid == 0) sflag = 0;

    // persistent Q fragments from packed q
    short8 qhi[2], qlo[2];
    float qn2;
    {
        int qrow = qt * 64 + wv * 16 + l16;
        const unsigned* qp = qpk + (size_t)qrow * DIN + h * HD;
        float sq = 0.f;
#pragma unroll
        for (int st = 0; st < 2; ++st) {
            const unsigned* p = qp + st * 32 + quad * 8;
            unpack8(*(const uint4*)p, *(const uint4*)(p + 4), qhi[st], qlo[st]);
#pragma unroll
            for (int j = 0; j < 8; ++j) {
                float f = bf2f((unsigned short)qhi[st][j]) + bf2f((unsigned short)qlo[st][j]);
                sq += f * f;
            }
        }
        sq += __shfl_xor(sq, 16);
        sq += __shfl_xor(sq, 32);
        qn2 = sq;
    }

    float tv[4][8]; int ti[4][8];
#pragma unroll
    for (int r = 0; r < 4; ++r)
#pragma unroll
        for (int s = 0; s < 8; ++s) { tv[r][s] = -FLT_MAX; ti[r][s] = 0x7FFFFFFF; }

    // ---- phase A: 2048 new keys (packed), 64 chunks of 32 ----
    for (int ch = 0; ch < 64; ++ch) {
        __syncthreads();
        {
            int key = tid >> 3, part = tid & 7;
            const unsigned* kr = kpk + (size_t)(ch * 32 + key) * DIN + h * HD + part * 8;
            short8 kh8, kl8;
            unpack8(*(const uint4*)kr, *(const uint4*)(kr + 4), kh8, kl8);
            *(short8*)&Khi[key * 72 + part * 8] = kh8;
            *(short8*)&Klo[key * 72 + part * 8] = kl8;
        }
        __syncthreads();

        short8 kh00 = *(const short8*)&Khi[l16 * 72 + quad * 8];
        short8 kh01 = *(const short8*)&Khi[l16 * 72 + 32 + quad * 8];
        short8 kl00 = *(const short8*)&Klo[l16 * 72 + quad * 8];
        short8 kl01 = *(const short8*)&Klo[l16 * 72 + 32 + quad * 8];
        short8 kh10 = *(const short8*)&Khi[(16 + l16) * 72 + quad * 8];
        short8 kh11 = *(const short8*)&Khi[(16 + l16) * 72 + 32 + quad * 8];
        short8 kl10 = *(const short8*)&Klo[(16 + l16) * 72 + quad * 8];
        short8 kl11 = *(const short8*)&Klo[(16 + l16) * 72 + 32 + quad * 8];
        floatx4 zero4 = {0.f, 0.f, 0.f, 0.f};
        floatx4 s0 = zero4, s1 = zero4;
        s0 = mfma16(qhi[0], kh00, s0); s0 = mfma16(qhi[1], kh01, s0);
        s0 = mfma16(qlo[0], kh00, s0); s0 = mfma16(qlo[1], kh01, s0);
        s0 = mfma16(qhi[0], kl00, s0); s0 = mfma16(qhi[1], kl01, s0);
        s1 = mfma16(qhi[0], kh10, s1); s1 = mfma16(qhi[1], kh11, s1);
        s1 = mfma16(qlo[0], kh10, s1); s1 = mfma16(qlo[1], kh11, s1);
        s1 = mfma16(qhi[0], kl10, s1); s1 = mfma16(qhi[1], kl11, s1);

        int base = OLDN + ch * 32;
#pragma unroll
        for (int r = 0; r < 4; ++r) {
            insert_top8(tv[r], ti[r], s0[r], base + l16);
            insert_top8(tv[r], ti[r], s1[r], base + 16 + l16);
        }
    }

    // ---- merge #1 across the 16 lanes of each quad ----
    float val8[4], keepv[4];
    int keepi[4];
#pragma unroll
    for (int rr = 0; rr < 4; ++rr) { keepv[rr] = -FLT_MAX; keepi[rr] = 0x7FFFFFFF; val8[rr] = -FLT_MAX; }
#pragma unroll
    for (int rr = 0; rr < 4; ++rr) {
#pragma unroll
        for (int m = 0; m < 8; ++m) {
            float cv = tv[rr][0]; int ci = ti[rr][0];
#pragma unroll
            for (int o = 1; o < 16; o <<= 1) {
                float ov = __shfl_xor(cv, o, 16);
                int oi = __shfl_xor(ci, o, 16);
                if (ov > cv || (ov == cv && oi < ci)) { cv = ov; ci = oi; }
            }
            if (tv[rr][0] == cv && ti[rr][0] == ci) {
#pragma unroll
                for (int s = 0; s < 7; ++s) { tv[rr][s] = tv[rr][s + 1]; ti[rr][s] = ti[rr][s + 1]; }
                tv[rr][7] = -FLT_MAX; ti[rr][7] = 0x7FFFFFFF;
            }
            if (l16 == m) { keepv[rr] = cv; keepi[rr] = ci; }
            if (l16 == 0)
                idxOut[((size_t)h * BN + qt * 64 + wv * 16 + quad * 4 + rr) * IPQ + m] = ci;
            val8[rr] = cv;
        }
    }

    // ---- bound check ----
    float oldMax = __uint_as_float(nrm[h]);
    bool need = false;
#pragma unroll
    for (int rr = 0; rr < 4; ++rr) {
        float bq = __shfl(qn2, quad * 4 + rr, 16);
        float bnd = sqrtf(bq) * oldMax * 1.0001f + 1e-5f;
        if (bnd >= val8[rr]) need = true;
    }
    if (need) sflag = 1;
    __syncthreads();

    if (sflag) {
#pragma unroll
        for (int rr = 0; rr < 4; ++rr) {
            tv[rr][0] = (l16 < 8) ? keepv[rr] : -FLT_MAX;
            ti[rr][0] = (l16 < 8) ? keepi[rr] : 0x7FFFFFFF;
#pragma unroll
            for (int s = 1; s < 8; ++s) { tv[rr][s] = -FLT_MAX; ti[rr][s] = 0x7FFFFFFF; }
        }
        for (int ch = 0; ch < 960; ++ch) {
            __syncthreads();
            {
                int key = tid >> 3, part = tid & 7;
                const float* kr = kmem0 + ((size_t)h * MEMN + BN + ch * 32 + key) * HD;
                short8 kh8, kl8;
                split_pack(*(const float4*)(kr + part * 8), *(const float4*)(kr + part * 8 + 4), kh8, kl8);
                *(short8*)&Khi[key * 72 + part * 8] = kh8;
                *(short8*)&Klo[key * 72 + part * 8] = kl8;
            }
            __syncthreads();

            short8 kh00 = *(const short8*)&Khi[l16 * 72 + quad * 8];
            short8 kh01 = *(const short8*)&Khi[l16 * 72 + 32 + quad * 8];
            short8 kl00 = *(const short8*)&Klo[l16 * 72 + quad * 8];
            short8 kl01 = *(const short8*)&Klo[l16 * 72 + 32 + quad * 8];
            short8 kh10 = *(const short8*)&Khi[(16 + l16) * 72 + quad * 8];
            short8 kh11 = *(const short8*)&Khi[(16 + l16) * 72 + 32 + quad * 8];
            short8 kl10 = *(const short8*)&Klo[(16 + l16) * 72 + quad * 8];
            short8 kl11 = *(const short8*)&Klo[(16 + l16) * 72 + 32 + quad * 8];
            floatx4 zero4 = {0.f, 0.f, 0.f, 0.f};
            floatx4 s0 = zero4, s1 = zero4;
            s0 = mfma16(qhi[0], kh00, s0); s0 = mfma16(qhi[1], kh01, s0);
            s0 = mfma16(qlo[0], kh00, s0); s0 = mfma16(qlo[1], kh01, s0);
            s0 = mfma16(qhi[0], kl00, s0); s0 = mfma16(qhi[1], kl01, s0);
            s1 = mfma16(qhi[0], kh10, s1); s1 = mfma16(qhi[1], kh11, s1);
            s1 = mfma16(qlo[0], kh10, s1); s1 = mfma16(qlo[1], kh11, s1);
            s1 = mfma16(qhi[0], kl10, s1); s1 = mfma16(qhi[1], kl11, s1);

            int base = ch * 32;
#pragma unroll
            for (int r = 0; r < 4; ++r) {
                insert_top8(tv[r], ti[r], s0[r], base + l16);
                insert_top8(tv[r], ti[r], s1[r], base + 16 + l16);
            }
        }
#pragma unroll
        for (int rr = 0; rr < 4; ++rr) {
#pragma unroll
            for (int m = 0; m < 8; ++m) {
                float cv = tv[rr][0]; int ci = ti[rr][0];
#pragma unroll
                for (int o = 1; o < 16; o <<= 1) {
                    float ov = __shfl_xor(cv, o, 16);
                    int oi = __shfl_xor(ci, o, 16);
                    if (ov > cv || (ov == cv && oi < ci)) { cv = ov; ci = oi; }
                }
                if (tv[rr][0] == cv && ti[rr][0] == ci) {
#pragma unroll
                    for (int s = 0; s < 7; ++s) { tv[rr][s] = tv[rr][s + 1]; ti[rr][s] = ti[rr][s + 1]; }
                    tv[rr][7] = -FLT_MAX; ti[rr][7] = 0x7FFFFFFF;
                }
                if (l16 == 0)
                    idxOut[((size_t)h * BN + qt * 64 + wv * 16 + quad * 4 + rr) * IPQ + m] = ci;
            }
        }
    }
}

// ---------------------------------------------------------------------------
// MFMA flash attention, merged. Grid (pid, mode, qt):
//   h = (pid&7) | ((pid>>3)&1)<<3, b = pid>>4  -> XCD x hosts heads {x,x+8}
//   (k/v packed slices 2MB, L2-resident for the new-key gathers).
//   mode 0: batch attn over 512 new keys -> normalized packed AO rows 0..2047
//   mode 1/2: gather halves (chunks 0..63 / 64..127) -> unnorm fp32 O + (m,l)
// idx prefetched 2 chunks ahead; K/V rows 1 chunk ahead. New rows load packed
// u32 (unpack at stage); old rows load fp32 (split at stage) - same registers.
// ---------------------------------------------------------------------------
__global__ __launch_bounds__(256, 2) void attn_kernel(
    const unsigned* __restrict__ qpk, const unsigned* __restrict__ kpk,
    const unsigned* __restrict__ vpk, const float* __restrict__ kmem0,
    const float* __restrict__ vmem0, const int* __restrict__ idxb,
    unsigned* __restrict__ AOpk, float* __restrict__ Gf, float* __restrict__ mlF)
{
    __shared__ short Khi[32 * 72];
    __shared__ short Klo[32 * 72];
    __shared__ short Vthi[64 * 40];
    __shared__ short Vtlo[64 * 40];
    __shared__ short Pbuf[4 * 16 * 40];
    int tid = threadIdx.x;
    int pid = blockIdx.x, mode = blockIdx.y, qt = blockIdx.z;
    int h = (pid & 7) | (((pid >> 3) & 1) << 3);
    int b = pid >> 4;
    int wv = tid >> 6, lane = tid & 63, quad = lane >> 4, l16 = lane & 15;

    // persistent Q fragments from packed q
    short8 qhi[2], qlo[2];
    {
        int qrow = b * NSEQ + qt * 64 + wv * 16 + l16;
        const unsigned* qp = qpk + (size_t)qrow * DIN + h * HD;
#pragma unroll
        for (int st = 0; st < 2; ++st) {
            const unsigned* p = qp + st * 32 + quad * 8;
            unpack8(*(const uint4*)p, *(const uint4*)(p + 4), qhi[st], qlo[st]);
        }
    }
    floatx4 zero4 = {0.f, 0.f, 0.f, 0.f};
    floatx4 Oacc[4];
#pragma unroll
    for (int t = 0; t < 4; ++t) Oacc[t] = zero4;
    float mrow[4], lrow[4];
#pragma unroll
    for (int r = 0; r < 4; ++r) { mrow[r] = -3.0e38f; lrow[r] = 0.f; }

    int key = tid >> 3, part = tid & 7;
    float4 ka, kb;      // K row: packed-u32 bits (new) or fp32 (old)
    float vvf[8];       // V dims part+8u: packed bits (new) or fp32 (old)
    bool isNew = true;

    auto loadIdx = [&](int chl) -> int {
        if (mode == 0) return 0;
        int J = chl * 32 + key;
        return idxb[((size_t)h * BN + b * NSEQ + (J >> 3)) * IPQ + (J & 7)];
    };
    auto gloadRows = [&](int chl, int mi) {
        if (mode == 0 || mi >= OLDN) {
            int row = (mode == 0) ? (b * NSEQ + chl * 32 + key) : (mi - OLDN);
            const unsigned* kr = kpk + (size_t)row * DIN + h * HD + part * 8;
            ka = *(const float4*)kr;
            kb = *(const float4*)(kr + 4);
            const unsigned* vr = vpk + (size_t)row * DIN + h * HD + part;
#pragma unroll
            for (int u = 0; u < 8; ++u) vvf[u] = __uint_as_float(vr[8 * u]);
            isNew = true;
        } else {
            const float* kr = kmem0 + ((size_t)h * MEMN + BN + mi) * HD + part * 8;
            ka = *(const float4*)kr;
            kb = *(const float4*)(kr + 4);
            const float* vr = vmem0 + ((size_t)h * MEMN + BN + mi) * HD + part;
#pragma unroll
            for (int u = 0; u < 8; ++u) vvf[u] = vr[8 * u];
            isNew = false;
        }
    };

    int ch0 = (mode == 2) ? 64 : 0;
    int ch1 = (mode == 0) ? 16 : ((mode == 1) ? 64 : 128);
    int miA = loadIdx(ch0);
    gloadRows(ch0, miA);
    int miB = loadIdx(ch0 + 1);
    for (int ch = ch0; ch < ch1; ++ch) {
        // barrier #1: previous chunk's LDS reads done before overwrite.
        // lgkmcnt only; in-flight global loads deliberately not drained.
        asm volatile("s_waitcnt lgkmcnt(0)" ::: "memory");
        __builtin_amdgcn_s_barrier();

        { // stage K row + V^T dims as bf16 hi/lo
            short8 kh8, kl8;
            if (isNew) unpack8f(ka, kb, kh8, kl8);
            else       split_pack(ka, kb, kh8, kl8);
            *(short8*)&Khi[key * 72 + part * 8] = kh8;
            *(short8*)&Klo[key * 72 + part * 8] = kl8;
            if (isNew) {
#pragma unroll
                for (int u = 0; u < 8; ++u) {
                    unsigned pv = __float_as_uint(vvf[u]);
                    Vthi[(part + 8 * u) * 40 + key] = (short)(pv & 0xFFFF);
                    Vtlo[(part + 8 * u) * 40 + key] = (short)(pv >> 16);
                }
            } else {
#pragma unroll
                for (int u = 0; u < 8; ++u) {
                    unsigned short hh = f2bf(vvf[u]);
                    Vthi[(part + 8 * u) * 40 + key] = (short)hh;
                    Vtlo[(part + 8 * u) * 40 + key] = (short)f2bf(vvf[u] - bf2f(hh));
                }
            }
        }
        if (ch + 1 < ch1) {
            gloadRows(ch + 1, miB);                    // rows: 1 chunk ahead
            if (ch + 2 < ch1) miB = loadIdx(ch + 2);   // idx: 2 chunks ahead
        }

        // barrier #2: staging visible to all waves (lgkmcnt only)
        asm volatile("s_waitcnt lgkmcnt(0)" ::: "memory");
        __builtin_amdgcn_s_barrier();

        // S = Q K^T (two 16-key col tiles), split-bf16 3-product
        short8 kh00 = *(const short8*)&Khi[(l16) * 72 + 0 * 32 + quad * 8];
        short8 kh01 = *(const short8*)&Khi[(l16) * 72 + 1 * 32 + quad * 8];
        short8 kl00 = *(const short8*)&Klo[(l16) * 72 + 0 * 32 + quad * 8];
        short8 kl01 = *(const short8*)&Klo[(l16) * 72 + 1 * 32 + quad * 8];
        short8 kh10 = *(const short8*)&Khi[(16 + l16) * 72 + 0 * 32 + quad * 8];
        short8 kh11 = *(const short8*)&Khi[(16 + l16) * 72 + 1 * 32 + quad * 8];
        short8 kl10 = *(const short8*)&Klo[(16 + l16) * 72 + 0 * 32 + quad * 8];
        short8 kl11 = *(const short8*)&Klo[(16 + l16) * 72 + 1 * 32 + quad * 8];
        floatx4 s0 = zero4, s1 = zero4;
        s0 = mfma16(qhi[0], kh00, s0); s0 = mfma16(qhi[1], kh01, s0);
        s0 = mfma16(qlo[0], kh00, s0); s0 = mfma16(qlo[1], kh01, s0);
        s0 = mfma16(qhi[0], kl00, s0); s0 = mfma16(qhi[1], kl01, s0);
        s1 = mfma16(qhi[0], kh10, s1); s1 = mfma16(qhi[1], kh11, s1);
        s1 = mfma16(qlo[0], kh10, s1); s1 = mfma16(qlo[1], kh11, s1);
        s1 = mfma16(qhi[0], kl10, s1); s1 = mfma16(qhi[1], kl11, s1);

        // online softmax (rows = quad*4+r, cols spread over 16 lanes)
        float cm[4], alpha[4], p0[4], p1[4], rs[4];
#pragma unroll
        for (int r = 0; r < 4; ++r) cm[r] = fmaxf(s0[r], s1[r]) * ATT_SCALE;
#pragma unroll
        for (int o = 1; o < 16; o <<= 1) {
#pragma unroll
            for (int r = 0; r < 4; ++r) cm[r] = fmaxf(cm[r], __shfl_xor(cm[r], o, 16));
        }
#pragma unroll
        for (int r = 0; r < 4; ++r) {
            float mn = fmaxf(mrow[r], cm[r]);
            alpha[r] = __expf(mrow[r] - mn);
            p0[r] = __expf(s0[r] * ATT_SCALE - mn);
            p1[r] = __expf(s1[r] * ATT_SCALE - mn);
            mrow[r] = mn;
            rs[r] = p0[r] + p1[r];
        }
#pragma unroll
        for (int o = 1; o < 16; o <<= 1) {
#pragma unroll
            for (int r = 0; r < 4; ++r) rs[r] += __shfl_xor(rs[r], o, 16);
        }
#pragma unroll
        for (int r = 0; r < 4; ++r) {
            lrow[r] = lrow[r] * alpha[r] + rs[r];
            Pbuf[(wv * 16 + quad * 4 + r) * 40 + l16]      = (short)f2bf(p0[r]);
            Pbuf[(wv * 16 + quad * 4 + r) * 40 + 16 + l16] = (short)f2bf(p1[r]);
        }
#pragma unroll
        for (int t = 0; t < 4; ++t)
#pragma unroll
            for (int r = 0; r < 4; ++r) Oacc[t][r] *= alpha[r];
        // Pbuf round-trip is per-wave: no barrier needed.

        short8 pf = *(const short8*)&Pbuf[(wv * 16 + l16) * 40 + quad * 8];
#pragma unroll
        for (int t = 0; t < 4; ++t) {
            short8 vh = *(const short8*)&Vthi[(t * 16 + l16) * 40 + quad * 8];
            short8 vl = *(const short8*)&Vtlo[(t * 16 + l16) * 40 + quad * 8];
            floatx4 o = Oacc[t];
            o = mfma16(pf, vh, o);
            o = mfma16(pf, vl, o);
            Oacc[t] = o;
        }
    }
    // epilogue
    if (mode == 0) {
#pragma unroll
        for (int t = 0; t < 4; ++t)
#pragma unroll
            for (int r = 0; r < 4; ++r) {
                int qrow = b * NSEQ + qt * 64 + wv * 16 + quad * 4 + r;
                AOpk[(size_t)qrow * DIN + h * HD + t * 16 + l16] = pack32(Oacc[t][r] / lrow[r]);
            }
    } else {
        float* ob = (mode == 1) ? Gf : (Gf + (size_t)2097152);
        float* mlbuf = mlF + ((size_t)(mode - 1) * NHEADS + h) * BN * 2;
#pragma unroll
        for (int t = 0; t < 4; ++t)
#pragma unroll
            for (int r = 0; r < 4; ++r) {
                int qrow = b * NSEQ + qt * 64 + wv * 16 + quad * 4 + r;
                ob[(size_t)qrow * DIN + h * HD + t * 16 + l16] = Oacc[t][r];
            }
        if (l16 == 0) {
#pragma unroll
            for (int r = 0; r < 4; ++r) {
                int qrow = b * NSEQ + qt * 64 + wv * 16 + quad * 4 + r;
                float2 mlv = {mrow[r], lrow[r]};
                *(float2*)&mlbuf[(size_t)qrow * 2] = mlv;
            }
        }
    }
}

// ---------------------------------------------------------------------------
// combine2: merge gather halves' partials -> packed a_m (AOpk rows 2048+).
// ---------------------------------------------------------------------------
__global__ __launch_bounds__(256) void combine2_kernel(
    const float* __restrict__ O0, const float* __restrict__ O1,
    const float* __restrict__ ml, unsigned* __restrict__ AOpkHalf)
{
    int g = blockIdx.x * 256 + threadIdx.x;   // f4 index, SZ/4 total
    int row = g >> 8;
    int h = (g >> 4) & 15;
    float2 ml0 = *(const float2*)&ml[((size_t)h * BN + row) * 2];
    float2 ml1 = *(const float2*)&ml[(((size_t)NHEADS + h) * BN + row) * 2];
    float m = fmaxf(ml0.x, ml1.x);
    float a0 = __expf(ml0.x - m), a1 = __expf(ml1.x - m);
    float inv = 1.f / (ml0.y * a0 + ml1.y * a1);
    float4 o0 = ((const float4*)O0)[g];
    float4 o1 = ((const float4*)O1)[g];
    uint4 po;
    po.x = pack32((o0.x * a0 + o1.x * a1) * inv);
    po.y = pack32((o0.y * a0 + o1.y * a1) * inv);
    po.z = pack32((o0.z * a0 + o1.z * a1) * inv);
    po.w = pack32((o0.w * a0 + o1.w * a1) * inv);
    ((uint4*)AOpkHalf)[g] = po;
}

// ---------------------------------------------------------------------------
// out = w*G1 + (1-w)*G2 + bo
// ---------------------------------------------------------------------------
__global__ __launch_bounds__(256) void combine_kernel(
    const float* __restrict__ G, const float* __restrict__ wg,
    const float* __restrict__ bo, float* __restrict__ out)
{
    int gid = blockIdx.x * 256 + threadIdx.x;     // f4 index, 524288 total
    float4 g1 = ((const float4*)G)[gid];
    float4 g2 = ((const float4*)G)[gid + (SZ / 4)];
    float4 w4 = ((const float4*)wg)[gid];
    float4 b4 = ((const float4*)bo)[gid & (DIN / 4 - 1)];
    float4 o;
    o.x = w4.x * g1.x + (1.f - w4.x) * g2.x + b4.x;
    o.y = w4.y * g1.y + (1.f - w4.y) * g2.y + b4.y;
    o.z = w4.z * g1.z + (1.f - w4.z) * g2.z + b4.z;
    o.w = w4.w * g1.w + (1.f - w4.w) * g2.w + b4.w;
    ((float4*)out)[gid] = o;
}

// ---------------------------------------------------------------------------
extern "C" void kernel_launch(void* const* d_in, const int* in_sizes, int n_in,
                              void* d_out, int out_size, void* d_ws, size_t ws_size,
                              hipStream_t stream)
{
    (void)in_sizes; (void)n_in; (void)out_size; (void)ws_size;
    const float* x     = (const float*)d_in[0];
    const float* Wq    = (const float*)d_in[1];
    const float* Wk    = (const float*)d_in[2];
    const float* Wv    = (const float*)d_in[3];
    const float* Ww    = (const float*)d_in[4];
    const float* Wo    = (const float*)d_in[5];
    const float* bo    = (const float*)d_in[6];
    const float* kmem0 = (const float*)d_in[7];
    const float* vmem0 = (const float*)d_in[8];

    char* W = (char*)d_ws;
    unsigned* PRJ  = (unsigned*)W;                       // qpk,kpk,vpk (8MB each)
    unsigned* qpk  = PRJ;
    unsigned* kpk  = PRJ + 2097152;
    unsigned* vpk  = PRJ + 2 * 2097152;
    float*    wg   = (float*)(W + WS_WG_OFF);
    unsigned* AOpk = (unsigned*)(W + WS_AOPK_OFF);       // [4096][1024]
    unsigned* xpk  = (unsigned*)(W + WS_XPK_OFF);        // pre-gemm1 scratch
    unsigned* Wpk  = (unsigned*)(W + WS_WPK_OFF);        // pre-gemm1 scratch
    float*    Gf   = (float*)(W + WS_GF_OFF);            // partials, then gemm2 out
    int*      idxb = (int*)(W + WS_IDX_OFF);
    float*    mlF  = (float*)(W + WS_ML_OFF);
    unsigned* nrm  = (unsigned*)(W + WS_NRM_OFF);
    unsigned* Wopk = (unsigned*)(W + WS_WOPK_OFF);

    init_kernel<<<1, 64, 0, stream>>>(nrm);
    presplit_kernel<<<dim3(2048, 1), 256, 0, stream>>>(x, x, x, x, xpk, 524288);
    presplit_kernel<<<dim3(1024, 4), 256, 0, stream>>>(Wq, Wk, Wv, Ww, Wpk, 262144);
    presplit_kernel<<<dim3(1024, 1), 256, 0, stream>>>(Wo, Wo, Wo, Wo, Wopk, 262144);
    gemm_pk<<<dim3(8, 16, 4), 256, 0, stream>>>(
        xpk, Wpk, Wpk + 1048576, Wpk + 2 * 1048576, Wpk + 3 * 1048576,
        PRJ, wg, 3, 3);
    oldnorm_kernel<<<dim3(30, 16), 256, 0, stream>>>(kmem0, nrm);
    search_kernel<<<dim3(16, 32), 256, 0, stream>>>(qpk, kpk, kmem0, nrm, idxb);
    attn_kernel<<<dim3(64, 3, 8), 256, 0, stream>>>(qpk, kpk, vpk, kmem0, vmem0,
                                                    idxb, AOpk, Gf, mlF);
    combine2_kernel<<<2048, 256, 0, stream>>>(Gf, Gf + (size_t)2097152, mlF,
                                              AOpk + (size_t)2048 * DIN);
    gemm_pk<<<dim3(8, 32, 1), 256, 0, stream>>>(
        AOpk, Wopk, Wopk, Wopk, Wopk, (unsigned*)nullptr, Gf, 0, -1);
    combine_kernel<<<2048, 256, 0, stream>>>(Gf, wg, bo, (float*)d_out);
}